// Round 8
// baseline (13502.138 us; speedup 1.0000x reference)
//
#include <hip/hip_runtime.h>
#include <hip/hip_bf16.h>

// Problem constants
#define B_  64
#define T_  256
#define D_  384
#define H_  6
#define HD_ 64
#define L_  6
#define V_  65
#define BT  (B_*T_)     // 16384 tokens

typedef __hip_bfloat16 bf16;
typedef unsigned short u16;

__device__ __forceinline__ float u2f(u16 u) {
  union { unsigned i; float f; } c; c.i = ((unsigned)u) << 16; return c.f;
}
__device__ __forceinline__ bf16 f2b(float x) { return __float2bfloat16(x); }
__device__ __forceinline__ float b2f(bf16 x) { return __bfloat162float(x); }

__device__ __forceinline__ float pload(const void* p, size_t i, bool f32w) {
  return f32w ? ((const float*)p)[i] : u2f(((const u16*)p)[i]);
}
__device__ __forceinline__ const void* eoff(const void* p, size_t e, bool f32w) {
  return (const void*)((const char*)p + e * (f32w ? 4u : 2u));
}

// ---------------------------------------------------------------------------
// Per-tensor dtype detect (R7, proven-consistent). flags[j], j=1..19: 1 => f32
// storage for float tensor j. flags[20]: 1 => idx int64.
// ---------------------------------------------------------------------------
__global__ void detect_kernel(
    const void* p1,  const void* p2,  const void* p3,  const void* p4,
    const void* p5,  const void* p6,  const void* p7,  const void* p8,
    const void* p9,  const void* p10, const void* p11, const void* p12,
    const void* p13, const void* p14, const void* p15, const void* p16,
    const void* p17, const void* p18, const void* p19,
    const int* __restrict__ idx, unsigned* flags)
{
  const void* ps[20] = {nullptr, p1, p2, p3, p4, p5, p6, p7, p8, p9, p10,
                        p11, p12, p13, p14, p15, p16, p17, p18, p19};
  const int esz[20] = {16384, 24960, 98304, 884736, 884736, 884736, 884736,
                       2304, 3538944, 9216, 3538944, 2304, 2304, 2304, 2304,
                       2304, 384, 384, 24960, 65};
  int tid = threadIdx.x;   // 64 threads, 1 wave
  if (tid == 0) {
    int zeros = 0;
    for (int m = 0; m < 4096; m++) zeros += (idx[2 * m + 1] == 0) ? 1 : 0;
    flags[20] = (zeros >= 4000) ? 1u : 0u;
  } else if (tid <= 19) {
    const u16* p = (const u16*)ps[tid];
    int ns = esz[tid] / 2; if (ns > 1024) ns = 1024;
    int band = 0, nz = 0;
    for (int i = 0; i < ns; i++) {
      u16 lo = p[2 * i], hi = p[2 * i + 1];
      int e = (lo >> 7) & 0xFF;
      band += (e >= 100 && e <= 127) ? 1 : 0;
      nz   += (lo | hi) ? 1 : 0;
    }
    flags[tid] = (nz > 0 && band * 2 < ns) ? 1u : 0u;   // 1 => f32 storage
  }
}

// Marker / fallback output (f32!)
__global__ void const_kernel(float* out, int n, float val) {
  int i = blockIdx.x * 256 + threadIdx.x;
  if (i < n) out[i] = val;
}

// ---------------------------------------------------------------------------
// Embedding: x = tok_emb[idx] + pos_emb[t]  (bf16 activation)
// ---------------------------------------------------------------------------
__global__ __launch_bounds__(256) void embed_kernel(
    const void* __restrict__ idx, const void* __restrict__ tok,
    const void* __restrict__ pos, bf16* __restrict__ x,
    const unsigned* __restrict__ flags)
{
  int i   = blockIdx.x * 256 + threadIdx.x;   // < BT*D_
  int tkn = i / D_;
  int d   = i - tkn * D_;
  int t   = tkn & (T_ - 1);
  long long tix;
  if (flags[20]) tix = ((const long long*)idx)[tkn];
  else           tix = ((const int*)idx)[tkn];
  float v = pload(tok, (size_t)tix * D_ + d, flags[1] != 0)
          + pload(pos, (size_t)t * D_ + d, flags[2] != 0);
  x[i] = f2b(v);
}

// ---------------------------------------------------------------------------
// Per-token LN stats: mean, rsqrt(var+eps). One wave per token.
// ---------------------------------------------------------------------------
__global__ __launch_bounds__(256) void stats_kernel(
    const bf16* __restrict__ x, float2* __restrict__ st)
{
  int w = threadIdx.x >> 6, lane = threadIdx.x & 63;
  int tok = blockIdx.x * 4 + w;
  const bf16* xr = x + (size_t)tok * D_;
  float v[6]; float s = 0.f;
#pragma unroll
  for (int j = 0; j < 6; j++) { v[j] = b2f(xr[lane + 64 * j]); s += v[j]; }
#pragma unroll
  for (int o = 1; o < 64; o <<= 1) s += __shfl_xor(s, o, 64);
  float mean = s * (1.0f / D_);
  float sq = 0.f;
#pragma unroll
  for (int j = 0; j < 6; j++) { float d0 = v[j] - mean; sq += d0 * d0; }
#pragma unroll
  for (int o = 1; o < 64; o <<= 1) sq += __shfl_xor(sq, o, 64);
  if (lane == 0) {
    float inv = 1.0f / sqrtf(sq * (1.0f / D_) + 1e-3f);
    st[tok] = make_float2(mean, inv);
  }
}

// ---------------------------------------------------------------------------
// Tiled GEMM (64x64 tile, BK=16, 4x4 microtile; exonerated bit-equivalent to
// naive in R3..R7). AMODE: fuse LN into A staging. OUTF32: f32 C store.
// ---------------------------------------------------------------------------
template<int AMODE, int RELU, int RESID, int F32W, int OUTF32>
__device__ __forceinline__ void gemm_core(
    const bf16* __restrict__ A, const float2* __restrict__ st,
    const void* __restrict__ lng, const void* __restrict__ lnb,
    bool fg, bool fb,
    const void* __restrict__ Bm, const void* __restrict__ bias, bool fbias,
    const bf16* __restrict__ resid, void* __restrict__ Cb,
    int N, int K, int arow0, int crow0, int n0)
{
  __shared__ float As[16][68];   // [k][m]
  __shared__ float Bs[16][68];   // [k][n]
  int tid = threadIdx.x;
  int tx = tid & 15, ty = tid >> 4;
  float acc[4][4] = {{0.f}};
  int am = tid >> 2;
  int ak = (tid & 3) << 2;
  int bk = tid >> 4;
  int bn = (tid & 15) << 2;
  int arow = arow0 + am;
  float mean = 0.f, inv = 1.f;
  if (AMODE) { float2 s2 = st[arow]; mean = s2.x; inv = s2.y; }
  const u16* Ap = (const u16*)A + (size_t)arow * K + ak;

  for (int k0 = 0; k0 < K; k0 += 16) {
    ushort4 au = *(const ushort4*)(Ap + k0);
    float a0 = u2f(au.x), a1 = u2f(au.y), a2 = u2f(au.z), a3 = u2f(au.w);
    if (AMODE) {
      int kk = k0 + ak;
      a0 = (a0 - mean) * inv * pload(lng, kk + 0, fg) + pload(lnb, kk + 0, fb);
      a1 = (a1 - mean) * inv * pload(lng, kk + 1, fg) + pload(lnb, kk + 1, fb);
      a2 = (a2 - mean) * inv * pload(lng, kk + 2, fg) + pload(lnb, kk + 2, fb);
      a3 = (a3 - mean) * inv * pload(lng, kk + 3, fg) + pload(lnb, kk + 3, fb);
    }
    float bv[4];
#pragma unroll
    for (int i = 0; i < 4; i++) {
      int n = n0 + bn + i;
      bv[i] = (n < N)
            ? (F32W ? ((const float*)Bm)[(size_t)(k0 + bk) * N + n]
                    : u2f(((const u16*)Bm)[(size_t)(k0 + bk) * N + n]))
            : 0.f;
    }
    __syncthreads();
    As[ak + 0][am] = a0; As[ak + 1][am] = a1;
    As[ak + 2][am] = a2; As[ak + 3][am] = a3;
    Bs[bk][bn + 0] = bv[0]; Bs[bk][bn + 1] = bv[1];
    Bs[bk][bn + 2] = bv[2]; Bs[bk][bn + 3] = bv[3];
    __syncthreads();
#pragma unroll
    for (int kk2 = 0; kk2 < 16; kk2++) {
      float4 a4 = *(const float4*)&As[kk2][ty << 2];
      float4 b4 = *(const float4*)&Bs[kk2][tx << 2];
      float a[4] = {a4.x, a4.y, a4.z, a4.w};
      float b[4] = {b4.x, b4.y, b4.z, b4.w};
#pragma unroll
      for (int i = 0; i < 4; i++)
#pragma unroll
        for (int j = 0; j < 4; j++)
          acc[i][j] += a[i] * b[j];
    }
  }

#pragma unroll
  for (int i = 0; i < 4; i++) {
    int cm = crow0 + (ty << 2) + i;
#pragma unroll
    for (int j = 0; j < 4; j++) {
      int n = n0 + (tx << 2) + j;
      if (n < N) {
        float val = acc[i][j];
        if (bias)  val += pload(bias, n, fbias);
        if (RESID) val += b2f(resid[(size_t)cm * N + n]);
        if (RELU)  val = fmaxf(val, 0.f);
        if (OUTF32) ((float*)Cb)[(size_t)cm * N + n] = val;
        else        ((bf16*)Cb)[(size_t)cm * N + n]  = f2b(val);
      }
    }
  }
}

// QKV (LN1-fused). grid (18, MCc/64). Chunk layout [mat][h][lm][hd].
__global__ __launch_bounds__(256) void qkv_kernel(
    const bf16* x, const float2* st, const void* lngb, const void* lnbb,
    size_t lnoff, const void* Wq, const void* Wk, const void* Wv,
    bf16* qkvc, int layer, int tok0, int MCc, const unsigned* flags)
{
  int zi  = blockIdx.x;
  int mat = zi / H_;
  int hh  = zi - mat * H_;
  bool fw = flags[3 + mat] != 0;
  bool fg = flags[12] != 0, fb = flags[13] != 0;
  const void* Wb = (mat == 0 ? Wq : mat == 1 ? Wk : Wv);
  const void* W  = eoff(Wb, (size_t)(layer * H_ + hh) * D_ * HD_, fw);
  const void* lg = eoff(lngb, lnoff, fg);
  const void* lb = eoff(lnbb, lnoff, fb);
  bf16* Cp = qkvc + (size_t)mat * MCc * D_ + (size_t)hh * MCc * HD_;
  int by = blockIdx.y * 64;
  if (fw) gemm_core<1,0,0,1,0>(x, st, lg, lb, fg, fb, W, nullptr, false,
                               nullptr, Cp, HD_, D_, tok0 + by, by, 0);
  else    gemm_core<1,0,0,0,0>(x, st, lg, lb, fg, fb, W, nullptr, false,
                               nullptr, Cp, HD_, D_, tok0 + by, by, 0);
}

// proj / ffn2: chunk-local A, +bias +resid, writes global x (bf16).
__global__ __launch_bounds__(256) void gemm_res_kernel(
    const bf16* A, const void* Bmb, size_t woff, const void* biasb,
    size_t boff, bf16* x, int N, int K, int tok0, int wfi, int bfi,
    const unsigned* flags)
{
  bool fw = flags[wfi] != 0, fbias = flags[bfi] != 0;
  const void* W  = eoff(Bmb, woff, fw);
  const void* bi = eoff(biasb, boff, fbias);
  int by = blockIdx.y * 64, n0 = blockIdx.x * 64;
  if (fw) gemm_core<0,0,1,1,0>(A, nullptr, nullptr, nullptr, false, false,
                               W, bi, fbias, x, x, N, K, by, tok0 + by, n0);
  else    gemm_core<0,0,1,0,0>(A, nullptr, nullptr, nullptr, false, false,
                               W, bi, fbias, x, x, N, K, by, tok0 + by, n0);
}

// ffn1: LN2-fused A = x (global rows), ReLU, writes mid chunk (local rows).
__global__ __launch_bounds__(256) void ffn1_kernel(
    const bf16* x, const float2* st, const void* lngb, const void* lnbb,
    size_t lnoff, const void* W1b, size_t woff, const void* b1b, size_t boff,
    bf16* midc, int tok0, const unsigned* flags)
{
  bool fw = flags[8] != 0, fbias = flags[9] != 0;
  bool fg = flags[14] != 0, fb = flags[15] != 0;
  const void* W  = eoff(W1b, woff, fw);
  const void* bi = eoff(b1b, boff, fbias);
  const void* lg = eoff(lngb, lnoff, fg);
  const void* lb = eoff(lnbb, lnoff, fb);
  int by = blockIdx.y * 64, n0 = blockIdx.x * 64;
  if (fw) gemm_core<1,1,0,1,0>(x, st, lg, lb, fg, fb, W, bi, fbias,
                               nullptr, midc, 4 * D_, D_, tok0 + by, by, n0);
  else    gemm_core<1,1,0,0,0>(x, st, lg, lb, fg, fb, W, bi, fbias,
                               nullptr, midc, 4 * D_, D_, tok0 + by, by, n0);
}

// head: LNf-fused A = x, +bias, ***FLOAT32*** out. grid (2, BT/64).
__global__ __launch_bounds__(256) void head_kernel(
    const bf16* x, const float2* st, const void* lng, const void* lnb,
    const void* Wh, const void* bh, float* out, const unsigned* flags)
{
  bool fw = flags[18] != 0, fbias = flags[19] != 0;
  bool fg = flags[16] != 0, fb = flags[17] != 0;
  int by = blockIdx.y * 64, n0 = blockIdx.x * 64;
  if (fw) gemm_core<1,0,0,1,1>(x, st, lng, lnb, fg, fb, Wh, bh, fbias,
                               nullptr, out, V_, D_, by, by, n0);
  else    gemm_core<1,0,0,0,1>(x, st, lng, lnb, fg, fb, Wh, bh, fbias,
                               nullptr, out, V_, D_, by, by, n0);
}

// ---------------------------------------------------------------------------
// LDS-free causal attention: one wave per query row (unchanged since R3).
// ---------------------------------------------------------------------------
__global__ __launch_bounds__(256) void attn2_kernel(
    const bf16* __restrict__ Q, const bf16* __restrict__ K,
    const bf16* __restrict__ V, bf16* __restrict__ att, int MCc)
{
  const float scale = 0.05103103630798288f;   // 384^-0.5 (full-D scaling!)
  int tid = threadIdx.x;
  int w = tid >> 6, lane = tid & 63;
  int gid = blockIdx.x * 4 + w;        // [0, H_*MCc)
  int h  = gid / MCc;
  int lm = gid - h * MCc;
  int bl = lm >> 8;
  int t  = lm & 255;
  int rowQ  = h * MCc + lm;
  int kbase = h * MCc + bl * T_;
  const u16* Qp = (const u16*)Q + ((size_t)rowQ << 6);
  const u16* Kp = (const u16*)K;
  const u16* Vp = (const u16*)V + (((size_t)kbase) << 6) + lane;

  int cmax = t >> 6;
  float sc[4] = {-1e30f, -1e30f, -1e30f, -1e30f};
  for (int c = 0; c <= cmax; c++) {
    int s = (c << 6) + lane;
    if (s <= t) {
      const u16* krow = Kp + ((size_t)(kbase + s) << 6);
      float dot = 0.f;
#pragma unroll
      for (int d = 0; d < 64; d += 4) {
        ushort4 kv = *(const ushort4*)(krow + d);
        ushort4 qv = *(const ushort4*)(Qp + d);
        dot += u2f(qv.x) * u2f(kv.x) + u2f(qv.y) * u2f(kv.y)
             + u2f(qv.z) * u2f(kv.z) + u2f(qv.w) * u2f(kv.w);
      }
      sc[c] = dot * scale;
    }
  }

  float m = fmaxf(fmaxf(sc[0], sc[1]), fmaxf(sc[2], sc[3]));
#pragma unroll
  for (int o2 = 1; o2 < 64; o2 <<= 1) m = fmaxf(m, __shfl_xor(m, o2, 64));
  float p[4]; float sum = 0.f;
#pragma unroll
  for (int c = 0; c < 4; c++) {
    p[c] = (sc[c] > -1e29f) ? __expf(sc[c] - m) : 0.f;
    sum += p[c];
  }
#pragma unroll
  for (int o2 = 1; o2 < 64; o2 <<= 1) sum += __shfl_xor(sum, o2, 64);

  float o = 0.f;
#pragma unroll
  for (int c = 0; c < 4; c++) {
    if (c > cmax) break;
    int jmax = t - (c << 6); if (jmax > 63) jmax = 63;
    for (int j = 0; j <= jmax; j++) {
      float pj = __shfl(p[c], j, 64);
      o += pj * u2f(Vp[(size_t)((c << 6) + j) << 6]);
    }
  }
  o /= sum;
  att[(size_t)lm * D_ + h * HD_ + lane] = f2b(o);
}

// ---------------------------------------------------------------------------
extern "C" void kernel_launch(void* const* d_in, const int* in_sizes, int n_in,
                              void* d_out, int out_size, void* d_ws, size_t ws_size,
                              hipStream_t stream)
{
  float* out = (float*)d_out;     // reference output dtype = float32 logits
  dim3 blk(256);
  int outg = (out_size + 255) / 256;

  // --- Host-side contract validation (f32 marker outputs on mismatch) ---
  static const int expected[20] = {
      16384, 24960, 98304, 884736, 884736, 884736, 884736, 2304,
      3538944, 9216, 3538944, 2304, 2304, 2304, 2304, 2304, 384, 384,
      24960, 65};
  if (n_in != 20) {
    const_kernel<<<outg, blk, 0, stream>>>(out, out_size, 5.0f);
    return;
  }
  for (int i = 0; i < 20; i++) {
    if (in_sizes[i] != expected[i]) {
      const_kernel<<<outg, blk, 0, stream>>>(out, out_size, 10.0f * (i + 1));
      return;
    }
  }
  if (out_size != BT * V_) {
    const_kernel<<<outg, blk, 0, stream>>>(out, out_size, 7.0f);
    return;
  }

  const void* idx   = d_in[0];
  const void* tok   = d_in[1];
  const void* pos   = d_in[2];
  const void* Wq    = d_in[3];
  const void* Wk    = d_in[4];
  const void* Wv    = d_in[5];
  const void* Wproj = d_in[6];
  const void* bproj = d_in[7];
  const void* W1    = d_in[8];
  const void* b1    = d_in[9];
  const void* W2    = d_in[10];
  const void* b2    = d_in[11];
  const void* ln1g  = d_in[12];
  const void* ln1b  = d_in[13];
  const void* ln2g  = d_in[14];
  const void* ln2b  = d_in[15];
  const void* lnfg  = d_in[16];
  const void* lnfb  = d_in[17];
  const void* Whead = d_in[18];
  const void* bhead = d_in[19];

  // Workspace: flags(256B) | x bf16[BT*D] | st float2[BT] | R bf16[MCc*4D]
  //   R = qkv(3*MCc*D) + att(MCc*D); mid(MCc*4D) overlays R exactly.
  const size_t fixed = 256 + (size_t)BT * D_ * 2 + (size_t)BT * 8;
  int nch = 0;
  const int cand[5] = {4, 8, 16, 32, 64};
  for (int i = 0; i < 5; i++) {
    size_t R = (size_t)(BT / cand[i]) * 4 * D_ * 2;
    if (fixed + R <= ws_size) { nch = cand[i]; break; }
  }
  if (nch == 0) {
    const_kernel<<<outg, blk, 0, stream>>>(out, out_size, 0.0f);  // ws signal
    return;
  }
  const int MCc = BT / nch;

  char* wsb = (char*)d_ws;
  unsigned* flags = (unsigned*)wsb;
  bf16*   x    = (bf16*)(wsb + 256);
  float2* st   = (float2*)(wsb + 256 + (size_t)BT * D_ * 2);
  bf16*   R    = (bf16*)(wsb + fixed);
  bf16*   qkvc = R;
  bf16*   attc = R + (size_t)3 * MCc * D_;
  bf16*   midc = R;

  detect_kernel<<<dim3(1), dim3(64), 0, stream>>>(
      tok, pos, Wq, Wk, Wv, Wproj, bproj, W1, b1, W2, b2,
      ln1g, ln1b, ln2g, ln2b, lnfg, lnfb, Whead, bhead,
      (const int*)idx, flags);
  embed_kernel<<<dim3(BT * D_ / 256), blk, 0, stream>>>(idx, tok, pos, x, flags);

  for (int l = 0; l < L_; l++) {
    stats_kernel<<<dim3(BT / 4), blk, 0, stream>>>(x, st);
    for (int c = 0; c < nch; c++) {
      int tok0 = c * MCc;
      qkv_kernel<<<dim3(18, MCc / 64), blk, 0, stream>>>(
          x, st, ln1g, ln1b, (size_t)l * D_, Wq, Wk, Wv, qkvc, l, tok0, MCc, flags);
      attn2_kernel<<<dim3(H_ * MCc / 4), blk, 0, stream>>>(
          qkvc, qkvc + (size_t)MCc * D_, qkvc + (size_t)2 * MCc * D_, attc, MCc);
      gemm_res_kernel<<<dim3(D_ / 64, MCc / 64), blk, 0, stream>>>(
          attc, Wproj, (size_t)l * D_ * D_, bproj, (size_t)l * D_,
          x, D_, D_, tok0, 6, 7, flags);
    }
    stats_kernel<<<dim3(BT / 4), blk, 0, stream>>>(x, st);
    for (int c = 0; c < nch; c++) {
      int tok0 = c * MCc;
      ffn1_kernel<<<dim3(4 * D_ / 64, MCc / 64), blk, 0, stream>>>(
          x, st, ln2g, ln2b, (size_t)l * D_, W1, (size_t)l * D_ * 4 * D_,
          b1, (size_t)l * 4 * D_, midc, tok0, flags);
      gemm_res_kernel<<<dim3(D_ / 64, MCc / 64), blk, 0, stream>>>(
          midc, W2, (size_t)l * 4 * D_ * D_, b2, (size_t)l * D_,
          x, D_, 4 * D_, tok0, 10, 11, flags);
    }
  }

  stats_kernel<<<dim3(BT / 4), blk, 0, stream>>>(x, st);
  head_kernel<<<dim3((V_ + 63) / 64, BT / 64), blk, 0, stream>>>(
      x, st, lnfg, lnfb, Whead, bhead, out, flags);
}

// Round 9
// 7942.776 us; speedup vs baseline: 1.6999x; 1.6999x over previous
//
#include <hip/hip_runtime.h>
#include <hip/hip_bf16.h>

// Problem constants
#define B_  64
#define T_  256
#define D_  384
#define H_  6
#define HD_ 64
#define L_  6
#define V_  65
#define BT  (B_*T_)     // 16384 tokens

typedef __hip_bfloat16 bf16;
typedef unsigned short u16;
typedef short s16;
typedef __attribute__((ext_vector_type(8))) short bf16x8;   // 8 bf16 = 4 VGPR
typedef __attribute__((ext_vector_type(4))) float f32x4;

__device__ __forceinline__ float u2f(u16 u) {
  union { unsigned i; float f; } c; c.i = ((unsigned)u) << 16; return c.f;
}
__device__ __forceinline__ bf16 f2b(float x) { return __float2bfloat16(x); }
__device__ __forceinline__ float b2f(bf16 x) { return __bfloat162float(x); }
__device__ __forceinline__ u16 f2u(float x) { bf16 h = f2b(x); return *(u16*)&h; }

__device__ __forceinline__ float pload(const void* p, size_t i, bool f32w) {
  return f32w ? ((const float*)p)[i] : u2f(((const u16*)p)[i]);
}
__device__ __forceinline__ const void* eoff(const void* p, size_t e, bool f32w) {
  return (const void*)((const char*)p + e * (f32w ? 4u : 2u));
}

// ---------------------------------------------------------------------------
// Parallel per-tensor dtype detect. Block j<19 -> tensor j+1; block 19 -> idx.
// flags[j]=1 => f32 storage; flags[20]=1 => idx int64.
// ---------------------------------------------------------------------------
__global__ __launch_bounds__(256) void detect_kernel(
    const void* p1,  const void* p2,  const void* p3,  const void* p4,
    const void* p5,  const void* p6,  const void* p7,  const void* p8,
    const void* p9,  const void* p10, const void* p11, const void* p12,
    const void* p13, const void* p14, const void* p15, const void* p16,
    const void* p17, const void* p18, const void* p19,
    const int* __restrict__ idx, unsigned* flags)
{
  const void* ps[20] = {nullptr, p1, p2, p3, p4, p5, p6, p7, p8, p9, p10,
                        p11, p12, p13, p14, p15, p16, p17, p18, p19};
  const int esz[20] = {16384, 24960, 98304, 884736, 884736, 884736, 884736,
                       2304, 3538944, 9216, 3538944, 2304, 2304, 2304, 2304,
                       2304, 384, 384, 24960, 65};
  __shared__ int r1[256], r2[256];
  int bid = blockIdx.x, tid = threadIdx.x;
  if (bid == 19) {                       // idx width
    int z = 0;
    for (int m = tid; m < 4096; m += 256) z += (idx[2 * m + 1] == 0) ? 1 : 0;
    r1[tid] = z; __syncthreads();
    for (int s = 128; s > 0; s >>= 1) {
      if (tid < s) r1[tid] += r1[tid + s];
      __syncthreads();
    }
    if (tid == 0) flags[20] = (r1[0] >= 4000) ? 1u : 0u;
    return;
  }
  int j = bid + 1;
  const u16* p = (const u16*)ps[j];
  int ns = esz[j] / 2; if (ns > 1024) ns = 1024;
  int band = 0, nz = 0;
  for (int i = tid; i < ns; i += 256) {
    u16 lo = p[2 * i], hi = p[2 * i + 1];
    int e = (lo >> 7) & 0xFF;
    band += (e >= 100 && e <= 127) ? 1 : 0;
    nz   += (lo | hi) ? 1 : 0;
  }
  r1[tid] = band; r2[tid] = nz; __syncthreads();
  for (int s = 128; s > 0; s >>= 1) {
    if (tid < s) { r1[tid] += r1[tid + s]; r2[tid] += r2[tid + s]; }
    __syncthreads();
  }
  if (tid == 0) flags[j] = (r2[0] > 0 && r1[0] * 2 < ns) ? 1u : 0u;
}

// Marker / fallback (f32 out)
__global__ void const_kernel(float* out, int n, float val) {
  int i = blockIdx.x * 256 + threadIdx.x;
  if (i < n) out[i] = val;
}

// ---------------------------------------------------------------------------
__global__ __launch_bounds__(256) void embed_kernel(
    const void* __restrict__ idx, const void* __restrict__ tok,
    const void* __restrict__ pos, bf16* __restrict__ x,
    const unsigned* __restrict__ flags)
{
  int i   = blockIdx.x * 256 + threadIdx.x;   // < BT*D_
  int tkn = i / D_;
  int d   = i - tkn * D_;
  int t   = tkn & (T_ - 1);
  long long tix;
  if (flags[20]) tix = ((const long long*)idx)[tkn];
  else           tix = ((const int*)idx)[tkn];
  float v = pload(tok, (size_t)tix * D_ + d, flags[1] != 0)
          + pload(pos, (size_t)t * D_ + d, flags[2] != 0);
  x[i] = f2b(v);
}

// ---------------------------------------------------------------------------
// LayerNorm: one wave per token -> h (chunk-local rows).
// ---------------------------------------------------------------------------
__global__ __launch_bounds__(256) void lnw_kernel(
    const bf16* __restrict__ x, bf16* __restrict__ h,
    const void* __restrict__ gb, const void* __restrict__ bb, size_t off,
    int tok0, int gfi, int bfi, const unsigned* __restrict__ flags)
{
  int w = threadIdx.x >> 6, lane = threadIdx.x & 63;
  int lm = blockIdx.x * 4 + w;
  const bf16* xr = x + (size_t)(tok0 + lm) * D_;
  float v[6]; float s = 0.f;
#pragma unroll
  for (int j = 0; j < 6; j++) { v[j] = b2f(xr[lane + 64 * j]); s += v[j]; }
#pragma unroll
  for (int o = 1; o < 64; o <<= 1) s += __shfl_xor(s, o, 64);
  float mean = s * (1.0f / D_);
  float sq = 0.f;
#pragma unroll
  for (int j = 0; j < 6; j++) { float d0 = v[j] - mean; sq += d0 * d0; }
#pragma unroll
  for (int o = 1; o < 64; o <<= 1) sq += __shfl_xor(sq, o, 64);
  float inv = 1.0f / sqrtf(sq * (1.0f / D_) + 1e-3f);
  bool fg = flags[gfi] != 0, fb = flags[bfi] != 0;
  bf16* hr = h + (size_t)lm * D_;
#pragma unroll
  for (int j = 0; j < 6; j++) {
    int d = lane + 64 * j;
    hr[d] = f2b((v[j] - mean) * inv * pload(gb, off + d, fg)
                + pload(bb, off + d, fb));
  }
}

// ---------------------------------------------------------------------------
// MFMA GEMM core. D = A·W: per-wave 32m x 64n via 16x16x32 bf16 MFMA.
// A (bf16, [M][K] chunk-local, ld=K) staged row-major; W ([K][N] global,
// dual-dtype) staged TRANSPOSED into LDS ([n][k]) so the B-fragment
// (B[n=lane&15][k=quad*8+j]) reads contiguous 16B. C/D: n=lane&15,
// m=quad*4+reg (guide m89/m91-verified).
// Tile: 128m x 64n x 64k. LDS: Xs 128x72, Wt 64x72 (pads keep hot ops
// <=2-way; b128-aligned).
// ---------------------------------------------------------------------------
#define XS_S 72
#define WT_S 72

template<int F32W, int RELU, int RESID, int OUTF32, int BIAS>
__device__ __forceinline__ void mgemm_core(
    s16* __restrict__ Xs, s16* __restrict__ Wt,
    const u16* __restrict__ A, const void* __restrict__ W,
    const void* __restrict__ bias, bool fbias,
    const bf16* __restrict__ resid, void* __restrict__ Cout,
    int ldC, int N, int K, int m0, int n0, int crow0)
{
  int tid = threadIdx.x;
  int w = tid >> 6, lane = tid & 63;
  int quad = lane >> 4, l15 = lane & 15;
  f32x4 acc[2][4];
#pragma unroll
  for (int i = 0; i < 2; i++)
#pragma unroll
    for (int j = 0; j < 4; j++) acc[i][j] = (f32x4){0.f, 0.f, 0.f, 0.f};

  int xr = tid >> 1, xc = (tid & 1) * 32;     // Xs staging coords
  int wn = tid & 31, wk8 = (tid >> 5) * 8;    // Wt staging coords

  for (int k0 = 0; k0 < K; k0 += 64) {
    // ---- load X (4 x 16B, coalesced) ----
    int4 xv[4];
    const u16* Ap = A + (size_t)(m0 + xr) * K + k0 + xc;
#pragma unroll
    for (int i = 0; i < 4; i++) xv[i] = *(const int4*)(Ap + 8 * i);
    // ---- load W with transpose into regs (8 k x 2 n per thread) ----
    bf16x8 wv0, wv1;
#pragma unroll
    for (int i = 0; i < 8; i++) {
      size_t krow = (size_t)(k0 + wk8 + i) * N;
      int na = n0 + wn, nb = n0 + wn + 32;
      if (F32W) {
        const float* Wp = (const float*)W;
        wv0[i] = (s16)f2u((na < N) ? Wp[krow + na] : 0.f);
        wv1[i] = (s16)f2u((nb < N) ? Wp[krow + nb] : 0.f);
      } else {
        const u16* Wp = (const u16*)W;
        wv0[i] = (s16)((na < N) ? Wp[krow + na] : (u16)0);
        wv1[i] = (s16)((nb < N) ? Wp[krow + nb] : (u16)0);
      }
    }
    __syncthreads();
#pragma unroll
    for (int i = 0; i < 4; i++)
      *(bf16x8*)&Xs[xr * XS_S + xc + 8 * i] = *(bf16x8*)&xv[i];
    *(bf16x8*)&Wt[wn * WT_S + wk8] = wv0;
    *(bf16x8*)&Wt[(wn + 32) * WT_S + wk8] = wv1;
    __syncthreads();
    // ---- MFMA: 2 k-halves x (2 m-subs x 4 n-tiles) ----
#pragma unroll
    for (int kh = 0; kh < 2; kh++) {
      int kk = kh * 32 + quad * 8;
      bf16x8 a0 = *(const bf16x8*)&Xs[(w * 32 + l15) * XS_S + kk];
      bf16x8 a1 = *(const bf16x8*)&Xs[(w * 32 + 16 + l15) * XS_S + kk];
#pragma unroll
      for (int nt = 0; nt < 4; nt++) {
        bf16x8 b = *(const bf16x8*)&Wt[(nt * 16 + l15) * WT_S + kk];
        acc[0][nt] = __builtin_amdgcn_mfma_f32_16x16x32_bf16(a0, b, acc[0][nt], 0, 0, 0);
        acc[1][nt] = __builtin_amdgcn_mfma_f32_16x16x32_bf16(a1, b, acc[1][nt], 0, 0, 0);
      }
    }
  }

  // ---- epilogue ----
#pragma unroll
  for (int sub = 0; sub < 2; sub++)
#pragma unroll
    for (int nt = 0; nt < 4; nt++)
#pragma unroll
      for (int r = 0; r < 4; r++) {
        int m = m0 + w * 32 + sub * 16 + quad * 4 + r;
        int n = n0 + nt * 16 + l15;
        if (n < N) {
          float v = acc[sub][nt][r];
          if (BIAS)  v += pload(bias, n, fbias);
          if (RESID) v += b2f(resid[(size_t)(crow0 + m) * ldC + n]);
          if (RELU)  v = fmaxf(v, 0.f);
          if (OUTF32) ((float*)Cout)[(size_t)(crow0 + m) * ldC + n] = v;
          else        ((bf16*)Cout)[(size_t)(crow0 + m) * ldC + n]  = f2b(v);
        }
      }
}

#define MGEMM_LDS __shared__ s16 Xs[128 * XS_S]; __shared__ s16 Wt[64 * WT_S];

// QKV: grid (MCc/128, 18). No bias. Out chunk layout [mat][head][m][64].
__global__ __launch_bounds__(256) void qkv_mfma(
    const bf16* hc, const void* Wq, const void* Wk, const void* Wv,
    bf16* qkvc, int layer, int MCc, const unsigned* flags)
{
  MGEMM_LDS
  int zi = blockIdx.y;
  int mat = zi / H_, hh = zi - mat * H_;
  bool fw = flags[3 + mat] != 0;
  const void* Wb = (mat == 0 ? Wq : mat == 1 ? Wk : Wv);
  const void* W  = eoff(Wb, (size_t)(layer * H_ + hh) * D_ * HD_, fw);
  bf16* Cp = qkvc + (size_t)mat * MCc * D_ + (size_t)hh * MCc * HD_;
  int m0 = blockIdx.x * 128;
  if (fw) mgemm_core<1,0,0,0,0>(Xs, Wt, (const u16*)hc, W, nullptr, false,
                                nullptr, Cp, HD_, HD_, D_, m0, 0, 0);
  else    mgemm_core<0,0,0,0,0>(Xs, Wt, (const u16*)hc, W, nullptr, false,
                                nullptr, Cp, HD_, HD_, D_, m0, 0, 0);
}

// proj / ffn2: +bias +resid(x), writes x. grid (N/64, MCc/128).
__global__ __launch_bounds__(256) void gemm_br_mfma(
    const bf16* A, const void* Wb, size_t woff, const void* biasb,
    size_t boff, bf16* x, int N, int K, int tok0, int wfi, int bfi,
    const unsigned* flags)
{
  MGEMM_LDS
  bool fw = flags[wfi] != 0, fb = flags[bfi] != 0;
  const void* W  = eoff(Wb, woff, fw);
  const void* bi = eoff(biasb, boff, fb);
  int n0 = blockIdx.x * 64, m0 = blockIdx.y * 128;
  if (fw) mgemm_core<1,0,1,0,1>(Xs, Wt, (const u16*)A, W, bi, fb,
                                x, x, N, N, K, m0, n0, tok0);
  else    mgemm_core<0,0,1,0,1>(Xs, Wt, (const u16*)A, W, bi, fb,
                                x, x, N, N, K, m0, n0, tok0);
}

// ffn1: +bias, ReLU, out midc (chunk-local). grid (24, MCc/128).
__global__ __launch_bounds__(256) void ffn1_mfma(
    const bf16* hc, const void* W1b, size_t woff, const void* b1b,
    size_t boff, bf16* midc, const unsigned* flags)
{
  MGEMM_LDS
  bool fw = flags[8] != 0, fb = flags[9] != 0;
  const void* W  = eoff(W1b, woff, fw);
  const void* bi = eoff(b1b, boff, fb);
  int n0 = blockIdx.x * 64, m0 = blockIdx.y * 128;
  if (fw) mgemm_core<1,1,0,0,1>(Xs, Wt, (const u16*)hc, W, bi, fb,
                                nullptr, midc, 4 * D_, 4 * D_, D_, m0, n0, 0);
  else    mgemm_core<0,1,0,0,1>(Xs, Wt, (const u16*)hc, W, bi, fb,
                                nullptr, midc, 4 * D_, 4 * D_, D_, m0, n0, 0);
}

// head: +bias, f32 out. grid (2, MCc/128). N=65 guarded.
__global__ __launch_bounds__(256) void head_mfma(
    const bf16* hc, const void* Wh, const void* bh, float* out, int tok0,
    const unsigned* flags)
{
  MGEMM_LDS
  bool fw = flags[18] != 0, fb = flags[19] != 0;
  int n0 = blockIdx.x * 64, m0 = blockIdx.y * 128;
  if (fw) mgemm_core<1,0,0,1,1>(Xs, Wt, (const u16*)hc, Wh, bh, fb,
                                nullptr, out, V_, V_, D_, m0, n0, tok0);
  else    mgemm_core<0,0,0,1,1>(Xs, Wt, (const u16*)hc, Wh, bh, fb,
                                nullptr, out, V_, V_, D_, m0, n0, tok0);
}

// ---------------------------------------------------------------------------
// LDS-staged causal attention: 4 q-rows/block (1/wave), K then V 64x64
// chunks staged cooperatively (coalesced ushort4), dots/AV from LDS.
// ---------------------------------------------------------------------------
__global__ __launch_bounds__(256) void attn_kernel(
    const bf16* __restrict__ Q, const bf16* __restrict__ K,
    const bf16* __restrict__ V, bf16* __restrict__ att, int MCc)
{
  __shared__ float chunk[64][65];
  __shared__ float qs[4][64];
  __shared__ float ps[4][64];
  const float scale = 0.05103103630798288f;   // 384^-0.5 (full-D scaling!)
  int tid = threadIdx.x;
  int w = tid >> 6, lane = tid & 63;
  int bid = blockIdx.x;
  int bh  = bid >> 6;                  // [0, (MCc/256)*H_)
  int t0  = (bid & 63) << 2;           // block-uniform
  int b = bh / H_, h = bh - b * H_;    // b chunk-local sequence
  size_t base = ((size_t)h * MCc + (size_t)b * T_) * HD_;
  int t = t0 + w;

  qs[w][lane] = b2f(Q[base + (size_t)t * HD_ + lane]);
  int cmax = t0 >> 6;                  // block-uniform
  float sc[4] = {-1e30f, -1e30f, -1e30f, -1e30f};

  for (int c = 0; c <= cmax; c++) {
    __syncthreads();
    const u16* src = (const u16*)K + base + ((size_t)c << 6) * HD_;
#pragma unroll
    for (int i = 0; i < 4; i++) {
      int e = i * 256 + tid;           // 1024 x ushort4
      int row = e >> 4;
      int c4 = (e & 15) << 2;
      ushort4 uv = *(const ushort4*)(src + row * HD_ + c4);
      chunk[row][c4 + 0] = u2f(uv.x); chunk[row][c4 + 1] = u2f(uv.y);
      chunk[row][c4 + 2] = u2f(uv.z); chunk[row][c4 + 3] = u2f(uv.w);
    }
    __syncthreads();
    int s = (c << 6) + lane;
    if (s <= t) {
      float dot = 0.f;
#pragma unroll
      for (int d = 0; d < 64; d++) dot += qs[w][d] * chunk[lane][d];
      sc[c] = dot * scale;
    }
  }

  float m = fmaxf(fmaxf(sc[0], sc[1]), fmaxf(sc[2], sc[3]));
#pragma unroll
  for (int o2 = 1; o2 < 64; o2 <<= 1) m = fmaxf(m, __shfl_xor(m, o2, 64));
  float p[4]; float sum = 0.f;
#pragma unroll
  for (int c = 0; c < 4; c++) {
    p[c] = (sc[c] > -1e29f) ? __expf(sc[c] - m) : 0.f;
    sum += p[c];
  }
#pragma unroll
  for (int o2 = 1; o2 < 64; o2 <<= 1) sum += __shfl_xor(sum, o2, 64);

  float o = 0.f;
  for (int c = 0; c <= cmax; c++) {
    __syncthreads();
    const u16* src = (const u16*)V + base + ((size_t)c << 6) * HD_;
#pragma unroll
    for (int i = 0; i < 4; i++) {
      int e = i * 256 + tid;
      int row = e >> 4;
      int c4 = (e & 15) << 2;
      ushort4 uv = *(const ushort4*)(src + row * HD_ + c4);
      chunk[row][c4 + 0] = u2f(uv.x); chunk[row][c4 + 1] = u2f(uv.y);
      chunk[row][c4 + 2] = u2f(uv.z); chunk[row][c4 + 3] = u2f(uv.w);
    }
    __syncthreads();
    ps[w][lane] = p[c];
    int jmax = t - (c << 6); if (jmax > 63) jmax = 63;
    for (int j = 0; j <= jmax; j++) o += ps[w][j] * chunk[j][lane];
  }
  o /= sum;
  att[(size_t)(b * T_ + t) * D_ + h * HD_ + lane] = f2b(o);
}

// ---------------------------------------------------------------------------
extern "C" void kernel_launch(void* const* d_in, const int* in_sizes, int n_in,
                              void* d_out, int out_size, void* d_ws, size_t ws_size,
                              hipStream_t stream)
{
  float* out = (float*)d_out;     // reference output dtype = float32 logits
  dim3 blk(256);
  int outg = (out_size + 255) / 256;

  static const int expected[20] = {
      16384, 24960, 98304, 884736, 884736, 884736, 884736, 2304,
      3538944, 9216, 3538944, 2304, 2304, 2304, 2304, 2304, 384, 384,
      24960, 65};
  if (n_in != 20) {
    const_kernel<<<outg, blk, 0, stream>>>(out, out_size, 5.0f);
    return;
  }
  for (int i = 0; i < 20; i++) {
    if (in_sizes[i] != expected[i]) {
      const_kernel<<<outg, blk, 0, stream>>>(out, out_size, 10.0f * (i + 1));
      return;
    }
  }
  if (out_size != BT * V_) {
    const_kernel<<<outg, blk, 0, stream>>>(out, out_size, 7.0f);
    return;
  }

  const void* idx   = d_in[0];
  const void* tok   = d_in[1];
  const void* pos   = d_in[2];
  const void* Wq    = d_in[3];
  const void* Wk    = d_in[4];
  const void* Wv    = d_in[5];
  const void* Wproj = d_in[6];
  const void* bproj = d_in[7];
  const void* W1    = d_in[8];
  const void* b1    = d_in[9];
  const void* W2    = d_in[10];
  const void* b2    = d_in[11];
  const void* ln1g  = d_in[12];
  const void* ln1b  = d_in[13];
  const void* ln2g  = d_in[14];
  const void* ln2b  = d_in[15];
  const void* lnfg  = d_in[16];
  const void* lnfb  = d_in[17];
  const void* Whead = d_in[18];
  const void* bhead = d_in[19];

  // Workspace: flags(256B) | x bf16[BT*D] | hc bf16[MCc*D] | R bf16[MCc*4D]
  //   R = qkv(3*MCc*D) + att(MCc*D); mid(MCc*4D) overlays R exactly.
  const size_t fixed = 256 + (size_t)BT * D_ * 2;
  int nch = 0;
  const int cand[5] = {4, 8, 16, 32, 64};
  for (int i = 0; i < 5; i++) {
    size_t scratch = (size_t)(BT / cand[i]) * (D_ + 4 * D_) * 2;  // h + R
    if (fixed + scratch <= ws_size) { nch = cand[i]; break; }
  }
  if (nch == 0) {
    const_kernel<<<outg, blk, 0, stream>>>(out, out_size, 0.0f);
    return;
  }
  const int MCc = BT / nch;

  char* wsb = (char*)d_ws;
  unsigned* flags = (unsigned*)wsb;
  bf16* x    = (bf16*)(wsb + 256);
  bf16* hc   = (bf16*)(wsb + fixed);
  bf16* R    = hc + (size_t)MCc * D_;
  bf16* qkvc = R;
  bf16* attc = R + (size_t)3 * MCc * D_;
  bf16* midc = R;

  detect_kernel<<<dim3(20), blk, 0, stream>>>(
      tok, pos, Wq, Wk, Wv, Wproj, bproj, W1, b1, W2, b2,
      ln1g, ln1b, ln2g, ln2b, lnfg, lnfb, Whead, bhead,
      (const int*)idx, flags);
  embed_kernel<<<dim3(BT * D_ / 256), blk, 0, stream>>>(idx, tok, pos, x, flags);

  int mtiles = MCc / 128;
  for (int l = 0; l < L_; l++) {
    for (int c = 0; c < nch; c++) {
      int tok0 = c * MCc;
      lnw_kernel<<<dim3(MCc / 4), blk, 0, stream>>>(
          x, hc, ln1g, ln1b, (size_t)l * D_, tok0, 12, 13, flags);
      qkv_mfma<<<dim3(mtiles, 18), blk, 0, stream>>>(
          hc, Wq, Wk, Wv, qkvc, l, MCc, flags);
      attn_kernel<<<dim3(H_ * MCc / 4), blk, 0, stream>>>(
          qkvc, qkvc + (size_t)MCc * D_, qkvc + (size_t)2 * MCc * D_, attc, MCc);
      gemm_br_mfma<<<dim3(6, mtiles), blk, 0, stream>>>(
          attc, Wproj, (size_t)l * D_ * D_, bproj, (size_t)l * D_,
          x, D_, D_, tok0, 6, 7, flags);
      lnw_kernel<<<dim3(MCc / 4), blk, 0, stream>>>(
          x, hc, ln2g, ln2b, (size_t)l * D_, tok0, 14, 15, flags);
      ffn1_mfma<<<dim3(24, mtiles), blk, 0, stream>>>(
          hc, W1, (size_t)l * D_ * 4 * D_, b1, (size_t)l * 4 * D_, midc, flags);
      gemm_br_mfma<<<dim3(6, mtiles), blk, 0, stream>>>(
          midc, W2, (size_t)l * 4 * D_ * D_, b2, (size_t)l * D_,
          x, D_, 4 * D_, tok0, 10, 11, flags);
    }
  }

  for (int c = 0; c < nch; c++) {
    int tok0 = c * MCc;
    lnw_kernel<<<dim3(MCc / 4), blk, 0, stream>>>(
        x, hc, lnfg, lnfb, 0, tok0, 16, 17, flags);
    head_mfma<<<dim3(2, mtiles), blk, 0, stream>>>(
        hc, Whead, bhead, out, tok0, flags);
  }
}

// Round 10
// 3388.780 us; speedup vs baseline: 3.9844x; 2.3438x over previous
//
#include <hip/hip_runtime.h>
#include <hip/hip_bf16.h>

// Problem constants
#define B_  64
#define T_  256
#define D_  384
#define H_  6
#define HD_ 64
#define L_  6
#define V_  65
#define BT  (B_*T_)     // 16384 tokens

typedef __hip_bfloat16 bf16;
typedef unsigned short u16;
typedef short s16;
typedef __attribute__((ext_vector_type(8))) short bf16x8;   // 8 bf16 = 4 VGPR
typedef __attribute__((ext_vector_type(4))) float f32x4;

// Per-layer weight buffer element offsets (bf16 elems)
#define OFF_QKV   0            // [mat][h][hd][d], 18 blocks of 24576
#define OFF_PROJ  442368       // [n][k] 384x384
#define OFF_W1T   589824       // [n][k] 1536x384
#define OFF_W2T   1179648      // [n][k] 384x1536
#define OFF_BPROJ 1769472
#define OFF_B1    1769856
#define OFF_B2    1771392
#define OFF_LN1G  1771776
#define OFF_LN1B  1772160
#define OFF_LN2G  1772544
#define OFF_LN2B  1772928
#define WBUF_E    1773312
// Head buffer
#define HOFF_WHT  0            // [n][k] 65x384
#define HOFF_BH   24960
#define HOFF_LNFG 25088
#define HOFF_LNFB 25472
#define HBUF_E    25856

__device__ __forceinline__ float u2f(u16 u) {
  union { unsigned i; float f; } c; c.i = ((unsigned)u) << 16; return c.f;
}
__device__ __forceinline__ bf16 f2b(float x) { return __float2bfloat16(x); }
__device__ __forceinline__ float b2f(bf16 x) { return __bfloat162float(x); }
__device__ __forceinline__ u16 f2u(float x) { bf16 h = f2b(x); return *(u16*)&h; }

__device__ __forceinline__ float pload(const void* p, size_t i, bool f32w) {
  return f32w ? ((const float*)p)[i] : u2f(((const u16*)p)[i]);
}

// ---------------------------------------------------------------------------
// Parallel per-tensor dtype detect (R8-proven). flags[j]=1 => f32 storage.
// flags[20]=1 => idx int64.
// ---------------------------------------------------------------------------
__global__ __launch_bounds__(256) void detect_kernel(
    const void* p1,  const void* p2,  const void* p3,  const void* p4,
    const void* p5,  const void* p6,  const void* p7,  const void* p8,
    const void* p9,  const void* p10, const void* p11, const void* p12,
    const void* p13, const void* p14, const void* p15, const void* p16,
    const void* p17, const void* p18, const void* p19,
    const int* __restrict__ idx, unsigned* flags)
{
  const void* ps[20] = {nullptr, p1, p2, p3, p4, p5, p6, p7, p8, p9, p10,
                        p11, p12, p13, p14, p15, p16, p17, p18, p19};
  const int esz[20] = {16384, 24960, 98304, 884736, 884736, 884736, 884736,
                       2304, 3538944, 9216, 3538944, 2304, 2304, 2304, 2304,
                       2304, 384, 384, 24960, 65};
  __shared__ int r1[256], r2[256];
  int bid = blockIdx.x, tid = threadIdx.x;
  if (bid == 19) {
    int z = 0;
    for (int m = tid; m < 4096; m += 256) z += (idx[2 * m + 1] == 0) ? 1 : 0;
    r1[tid] = z; __syncthreads();
    for (int s = 128; s > 0; s >>= 1) {
      if (tid < s) r1[tid] += r1[tid + s];
      __syncthreads();
    }
    if (tid == 0) flags[20] = (r1[0] >= 4000) ? 1u : 0u;
    return;
  }
  int j = bid + 1;
  const u16* p = (const u16*)ps[j];
  int ns = esz[j] / 2; if (ns > 1024) ns = 1024;
  int band = 0, nz = 0;
  for (int i = tid; i < ns; i += 256) {
    u16 lo = p[2 * i], hi = p[2 * i + 1];
    int e = (lo >> 7) & 0xFF;
    band += (e >= 100 && e <= 127) ? 1 : 0;
    nz   += (lo | hi) ? 1 : 0;
  }
  r1[tid] = band; r2[tid] = nz; __syncthreads();
  for (int s = 128; s > 0; s >>= 1) {
    if (tid < s) { r1[tid] += r1[tid + s]; r2[tid] += r2[tid + s]; }
    __syncthreads();
  }
  if (tid == 0) flags[j] = (r2[0] > 0 && r1[0] * 2 < ns) ? 1u : 0u;
}

__global__ void const_kernel(float* out, int n, float val) {
  int i = blockIdx.x * 256 + threadIdx.x;
  if (i < n) out[i] = val;
}

// ---------------------------------------------------------------------------
// Per-layer weight convert+transpose to bf16. One thread per dst element.
// ---------------------------------------------------------------------------
__global__ __launch_bounds__(256) void conv_layer(
    const void* Wq, const void* Wk, const void* Wv, const void* Wproj,
    const void* bproj, const void* W1, const void* b1, const void* W2,
    const void* b2, const void* ln1g, const void* ln1b, const void* ln2g,
    const void* ln2b, const unsigned* __restrict__ flags,
    bf16* __restrict__ dst, int l)
{
  int e = blockIdx.x * 256 + threadIdx.x;
  if (e >= WBUF_E) return;
  float v;
  if (e < OFF_PROJ) {                       // QKV^T per head
    int math = e / 24576;
    int rem  = e - math * 24576;
    int hd = rem / 384, d = rem - hd * 384;
    int mat = math / 6, hh = math - mat * 6;
    const void* src = (mat == 0 ? Wq : mat == 1 ? Wk : Wv);
    v = pload(src, ((size_t)(l * 6 + hh) * 384 + d) * 64 + hd, flags[3 + mat] != 0);
  } else if (e < OFF_W1T) {                 // Wproj^T
    int e2 = e - OFF_PROJ;
    int n = e2 / 384, d = e2 - n * 384;
    v = pload(Wproj, ((size_t)l * 384 + d) * 384 + n, flags[6] != 0);
  } else if (e < OFF_W2T) {                 // W1^T
    int e2 = e - OFF_W1T;
    int n = e2 / 384, d = e2 - n * 384;
    v = pload(W1, ((size_t)l * 384 + d) * 1536 + n, flags[8] != 0);
  } else if (e < OFF_BPROJ) {               // W2^T
    int e2 = e - OFF_W2T;
    int n = e2 / 1536, k = e2 - n * 1536;
    v = pload(W2, ((size_t)l * 1536 + k) * 384 + n, flags[10] != 0);
  } else {
    int e2 = e - OFF_BPROJ;
    if      (e2 < 384)  v = pload(bproj, (size_t)l * 384 + e2, flags[7] != 0);
    else if (e2 < 1920) v = pload(b1, (size_t)l * 1536 + (e2 - 384), flags[9] != 0);
    else if (e2 < 2304) v = pload(b2, (size_t)l * 384 + (e2 - 1920), flags[11] != 0);
    else if (e2 < 2688) v = pload(ln1g, (size_t)l * 384 + (e2 - 2304), flags[12] != 0);
    else if (e2 < 3072) v = pload(ln1b, (size_t)l * 384 + (e2 - 2688), flags[13] != 0);
    else if (e2 < 3456) v = pload(ln2g, (size_t)l * 384 + (e2 - 3072), flags[14] != 0);
    else                v = pload(ln2b, (size_t)l * 384 + (e2 - 3456), flags[15] != 0);
  }
  dst[e] = f2b(v);
}

__global__ __launch_bounds__(256) void conv_head(
    const void* Wh, const void* bh, const void* lnfg, const void* lnfb,
    const unsigned* __restrict__ flags, bf16* __restrict__ dst)
{
  int e = blockIdx.x * 256 + threadIdx.x;
  if (e >= HBUF_E) return;
  float v = 0.f;
  if (e < HOFF_BH) {                        // Whead^T [65][384]
    int n = e / 384, d = e - n * 384;
    v = pload(Wh, (size_t)d * 65 + n, flags[18] != 0);
  } else if (e < 25025) {
    v = pload(bh, e - HOFF_BH, flags[19] != 0);
  } else if (e < HOFF_LNFG) {
    v = 0.f;                                // pad
  } else if (e < HOFF_LNFB) {
    v = pload(lnfg, e - HOFF_LNFG, flags[16] != 0);
  } else {
    v = pload(lnfb, e - HOFF_LNFB, flags[17] != 0);
  }
  dst[e] = f2b(v);
}

// ---------------------------------------------------------------------------
__global__ __launch_bounds__(256) void embed_kernel(
    const void* __restrict__ idx, const void* __restrict__ tok,
    const void* __restrict__ pos, bf16* __restrict__ x,
    const unsigned* __restrict__ flags)
{
  int i   = blockIdx.x * 256 + threadIdx.x;   // < BT*D_
  int tkn = i / D_;
  int d   = i - tkn * D_;
  int t   = tkn & (T_ - 1);
  long long tix;
  if (flags[20]) tix = ((const long long*)idx)[tkn];
  else           tix = ((const int*)idx)[tkn];
  float v = pload(tok, (size_t)tix * D_ + d, flags[1] != 0)
          + pload(pos, (size_t)t * D_ + d, flags[2] != 0);
  x[i] = f2b(v);
}

// ---------------------------------------------------------------------------
// Per-token LN stats: mean, rsqrt(var+eps). One wave per token.
// ---------------------------------------------------------------------------
__global__ __launch_bounds__(256) void stats_kernel(
    const bf16* __restrict__ x, float2* __restrict__ st)
{
  int w = threadIdx.x >> 6, lane = threadIdx.x & 63;
  int tok = blockIdx.x * 4 + w;
  const bf16* xr = x + (size_t)tok * D_;
  float v[6]; float s = 0.f;
#pragma unroll
  for (int j = 0; j < 6; j++) { v[j] = b2f(xr[lane + 64 * j]); s += v[j]; }
#pragma unroll
  for (int o = 1; o < 64; o <<= 1) s += __shfl_xor(s, o, 64);
  float mean = s * (1.0f / D_);
  float sq = 0.f;
#pragma unroll
  for (int j = 0; j < 6; j++) { float d0 = v[j] - mean; sq += d0 * d0; }
#pragma unroll
  for (int o = 1; o < 64; o <<= 1) sq += __shfl_xor(sq, o, 64);
  if (lane == 0) {
    float inv = 1.0f / sqrtf(sq * (1.0f / D_) + 1e-3f);
    st[tok] = make_float2(mean, inv);
  }
}

// ---------------------------------------------------------------------------
// MFMA GEMM core. Tile 128m x 64n x 64k, 256 thr (4 waves, 32m each).
// All operands bf16. W is PRE-TRANSPOSED [N][K] -> vector staging, no
// branches in the hot loop. AMODE: LayerNorm fused into A staging via st +
// bf16 g/b. Fragment maps HW-verified in R9.
// ---------------------------------------------------------------------------
#define XS_S 72
#define WT_S 72

template<int AMODE, int RELU, int RESID, int OUTF32, int BIAS>
__device__ __forceinline__ void mgemm_core(
    s16* __restrict__ Xs, s16* __restrict__ Wt,
    const u16* __restrict__ A, const float2* __restrict__ st,
    const u16* __restrict__ lng, const u16* __restrict__ lnb,
    const u16* __restrict__ WT, const bf16* __restrict__ bias,
    const bf16* __restrict__ resid, void* __restrict__ Cout,
    int ldC, int N, int K, int arow0, int crow0, int n0)
{
  int tid = threadIdx.x;
  int w = tid >> 6, lane = tid & 63;
  int quad = lane >> 4, l15 = lane & 15;
  f32x4 acc[2][4];
#pragma unroll
  for (int i = 0; i < 2; i++)
#pragma unroll
    for (int j = 0; j < 4; j++) acc[i][j] = (f32x4){0.f, 0.f, 0.f, 0.f};

  int xr = tid >> 1, xc = (tid & 1) * 32;     // X staging: 128 rows x 32 k
  int wn = tid >> 2, wk = (tid & 3) * 16;     // W staging: 64 rows x 16 k
  float mean = 0.f, inv = 1.f;
  if (AMODE) { float2 s2 = st[arow0 + xr]; mean = s2.x; inv = s2.y; }
  const u16* Ap0 = A + (size_t)(arow0 + xr) * K + xc;
  bool wvalid = (n0 + wn) < N;
  const u16* Wp0 = WT + (size_t)(wvalid ? (n0 + wn) : 0) * K + wk;

  for (int k0 = 0; k0 < K; k0 += 64) {
    bf16x8 xv[4];
#pragma unroll
    for (int i = 0; i < 4; i++) xv[i] = *(const bf16x8*)(Ap0 + k0 + 8 * i);
    if (AMODE) {
#pragma unroll
      for (int i = 0; i < 4; i++) {
        bf16x8 g = *(const bf16x8*)(lng + xc + k0 + 8 * i);
        bf16x8 b = *(const bf16x8*)(lnb + xc + k0 + 8 * i);
#pragma unroll
        for (int j = 0; j < 8; j++) {
          float f = (u2f((u16)xv[i][j]) - mean) * inv * u2f((u16)g[j])
                  + u2f((u16)b[j]);
          xv[i][j] = (s16)f2u(f);
        }
      }
    }
    bf16x8 wv[2];
#pragma unroll
    for (int i = 0; i < 2; i++)
      wv[i] = wvalid ? *(const bf16x8*)(Wp0 + k0 + 8 * i)
                     : (bf16x8){0,0,0,0,0,0,0,0};
    __syncthreads();
#pragma unroll
    for (int i = 0; i < 4; i++)
      *(bf16x8*)&Xs[xr * XS_S + xc + 8 * i] = xv[i];
#pragma unroll
    for (int i = 0; i < 2; i++)
      *(bf16x8*)&Wt[wn * WT_S + wk + 8 * i] = wv[i];
    __syncthreads();
#pragma unroll
    for (int kh = 0; kh < 2; kh++) {
      int kk = kh * 32 + quad * 8;
      bf16x8 a0 = *(const bf16x8*)&Xs[(w * 32 + l15) * XS_S + kk];
      bf16x8 a1 = *(const bf16x8*)&Xs[(w * 32 + 16 + l15) * XS_S + kk];
#pragma unroll
      for (int nt = 0; nt < 4; nt++) {
        bf16x8 b = *(const bf16x8*)&Wt[(nt * 16 + l15) * WT_S + kk];
        acc[0][nt] = __builtin_amdgcn_mfma_f32_16x16x32_bf16(a0, b, acc[0][nt], 0, 0, 0);
        acc[1][nt] = __builtin_amdgcn_mfma_f32_16x16x32_bf16(a1, b, acc[1][nt], 0, 0, 0);
      }
    }
  }

#pragma unroll
  for (int sub = 0; sub < 2; sub++)
#pragma unroll
    for (int nt = 0; nt < 4; nt++)
#pragma unroll
      for (int r = 0; r < 4; r++) {
        int m = w * 32 + sub * 16 + quad * 4 + r;     // tile-local
        int n = n0 + nt * 16 + l15;
        if (n < N) {
          float v = acc[sub][nt][r];
          if (BIAS)  v += b2f(bias[n]);
          if (RESID) v += b2f(resid[(size_t)(crow0 + m) * ldC + n]);
          if (RELU)  v = fmaxf(v, 0.f);
          if (OUTF32) ((float*)Cout)[(size_t)(crow0 + m) * ldC + n] = v;
          else        ((bf16*)Cout)[(size_t)(crow0 + m) * ldC + n]  = f2b(v);
        }
      }
}

#define MGEMM_LDS __shared__ s16 Xs[128 * XS_S]; __shared__ s16 Wt[64 * WT_S];

// QKV: LN1-fused. grid (MCa/128, 18). Out chunk layout [mat][h][m][64].
__global__ __launch_bounds__(256) void qkv_mfma(
    const bf16* x, const float2* st, const bf16* Wbuf, bf16* qkvc,
    int MCa, int tok0)
{
  MGEMM_LDS
  int zi = blockIdx.y;
  int mat = zi / H_, hh = zi - mat * H_;
  const u16* W = (const u16*)Wbuf + OFF_QKV + (size_t)zi * HD_ * D_;
  bf16* Cp = qkvc + (size_t)mat * MCa * D_ + (size_t)hh * MCa * HD_;
  int m0 = blockIdx.x * 128;
  mgemm_core<1,0,0,0,0>(Xs, Wt, (const u16*)x, st,
                        (const u16*)Wbuf + OFF_LN1G, (const u16*)Wbuf + OFF_LN1B,
                        W, nullptr, nullptr, Cp, HD_, HD_, D_,
                        tok0 + m0, m0, 0);
}

// proj: A rows + resid/out x rows share crow base. grid (6, M/128).
__global__ __launch_bounds__(256) void proj_mfma(
    const bf16* A, const bf16* Wbuf, bf16* x, int tok0)
{
  MGEMM_LDS
  int n0 = blockIdx.x * 64, m0 = blockIdx.y * 128;
  mgemm_core<0,0,1,0,1>(Xs, Wt, (const u16*)A, nullptr, nullptr, nullptr,
                        (const u16*)Wbuf + OFF_PROJ, (const bf16*)Wbuf + OFF_BPROJ,
                        x, x, D_, D_, D_, m0, tok0 + m0, n0);
}

// ffn1: LN2-fused, ReLU. grid (24, MCf/128). Out midc local rows.
__global__ __launch_bounds__(256) void ffn1_mfma(
    const bf16* x, const float2* st, const bf16* Wbuf, bf16* midc, int tok0)
{
  MGEMM_LDS
  int n0 = blockIdx.x * 64, m0 = blockIdx.y * 128;
  mgemm_core<1,1,0,0,1>(Xs, Wt, (const u16*)x, st,
                        (const u16*)Wbuf + OFF_LN2G, (const u16*)Wbuf + OFF_LN2B,
                        (const u16*)Wbuf + OFF_W1T, (const bf16*)Wbuf + OFF_B1,
                        nullptr, midc, 4 * D_, 4 * D_, D_,
                        tok0 + m0, m0, n0);
}

// ffn2: +bias +resid. grid (6, MCf/128).
__global__ __launch_bounds__(256) void ffn2_mfma(
    const bf16* midc, const bf16* Wbuf, bf16* x, int tok0)
{
  MGEMM_LDS
  int n0 = blockIdx.x * 64, m0 = blockIdx.y * 128;
  mgemm_core<0,0,1,0,1>(Xs, Wt, (const u16*)midc, nullptr, nullptr, nullptr,
                        (const u16*)Wbuf + OFF_W2T, (const bf16*)Wbuf + OFF_B2,
                        x, x, D_, D_, 4 * D_, m0, tok0 + m0, n0);
}

// head: LNf-fused, f32 out. grid (2, 128). N=65 (staging guard handles OOB).
__global__ __launch_bounds__(256) void head_mfma(
    const bf16* x, const float2* st, const bf16* Hbuf, float* out)
{
  MGEMM_LDS
  int n0 = blockIdx.x * 64, m0 = blockIdx.y * 128;
  mgemm_core<1,0,0,1,1>(Xs, Wt, (const u16*)x, st,
                        (const u16*)Hbuf + HOFF_LNFG, (const u16*)Hbuf + HOFF_LNFB,
                        (const u16*)Hbuf + HOFF_WHT, (const bf16*)Hbuf + HOFF_BH,
                        nullptr, out, V_, V_, D_, m0, m0, n0);
}

// ---------------------------------------------------------------------------
// LDS-staged causal attention (R9-proven). row0: output row base.
// ---------------------------------------------------------------------------
__global__ __launch_bounds__(256) void attn_kernel(
    const bf16* __restrict__ Q, const bf16* __restrict__ K,
    const bf16* __restrict__ V, bf16* __restrict__ att, int MCa, int row0)
{
  __shared__ float chunk[64][65];
  __shared__ float qs[4][64];
  __shared__ float ps[4][64];
  const float scale = 0.05103103630798288f;   // 384^-0.5 (full-D scaling!)
  int tid = threadIdx.x;
  int w = tid >> 6, lane = tid & 63;
  int bid = blockIdx.x;
  int bh  = bid >> 6;
  int t0  = (bid & 63) << 2;
  int b = bh / H_, h = bh - b * H_;
  size_t base = ((size_t)h * MCa + (size_t)b * T_) * HD_;
  int t = t0 + w;

  qs[w][lane] = b2f(Q[base + (size_t)t * HD_ + lane]);
  int cmax = t0 >> 6;
  float sc[4] = {-1e30f, -1e30f, -1e30f, -1e30f};

  for (int c = 0; c <= cmax; c++) {
    __syncthreads();
    const u16* src = (const u16*)K + base + ((size_t)c << 6) * HD_;
#pragma unroll
    for (int i = 0; i < 4; i++) {
      int e = i * 256 + tid;
      int row = e >> 4;
      int c4 = (e & 15) << 2;
      ushort4 uv = *(const ushort4*)(src + row * HD_ + c4);
      chunk[row][c4 + 0] = u2f(uv.x); chunk[row][c4 + 1] = u2f(uv.y);
      chunk[row][c4 + 2] = u2f(uv.z); chunk[row][c4 + 3] = u2f(uv.w);
    }
    __syncthreads();
    int s = (c << 6) + lane;
    if (s <= t) {
      float dot = 0.f;
#pragma unroll
      for (int d = 0; d < 64; d++) dot += qs[w][d] * chunk[lane][d];
      sc[c] = dot * scale;
    }
  }

  float m = fmaxf(fmaxf(sc[0], sc[1]), fmaxf(sc[2], sc[3]));
#pragma unroll
  for (int o2 = 1; o2 < 64; o2 <<= 1) m = fmaxf(m, __shfl_xor(m, o2, 64));
  float p[4]; float sum = 0.f;
#pragma unroll
  for (int c = 0; c < 4; c++) {
    p[c] = (sc[c] > -1e29f) ? __expf(sc[c] - m) : 0.f;
    sum += p[c];
  }
#pragma unroll
  for (int o2 = 1; o2 < 64; o2 <<= 1) sum += __shfl_xor(sum, o2, 64);

  float o = 0.f;
  for (int c = 0; c <= cmax; c++) {
    __syncthreads();
    const u16* src = (const u16*)V + base + ((size_t)c << 6) * HD_;
#pragma unroll
    for (int i = 0; i < 4; i++) {
      int e = i * 256 + tid;
      int row = e >> 4;
      int c4 = (e & 15) << 2;
      ushort4 uv = *(const ushort4*)(src + row * HD_ + c4);
      chunk[row][c4 + 0] = u2f(uv.x); chunk[row][c4 + 1] = u2f(uv.y);
      chunk[row][c4 + 2] = u2f(uv.z); chunk[row][c4 + 3] = u2f(uv.w);
    }
    __syncthreads();
    ps[w][lane] = p[c];
    int jmax = t - (c << 6); if (jmax > 63) jmax = 63;
    for (int j = 0; j <= jmax; j++) o += ps[w][j] * chunk[j][lane];
  }
  o /= sum;
  att[(size_t)(row0 + b * T_ + t) * D_ + h * HD_ + lane] = f2b(o);
}

// ---------------------------------------------------------------------------
extern "C" void kernel_launch(void* const* d_in, const int* in_sizes, int n_in,
                              void* d_out, int out_size, void* d_ws, size_t ws_size,
                              hipStream_t stream)
{
  float* out = (float*)d_out;
  dim3 blk(256);
  int outg = (out_size + 255) / 256;

  static const int expected[20] = {
      16384, 24960, 98304, 884736, 884736, 884736, 884736, 2304,
      3538944, 9216, 3538944, 2304, 2304, 2304, 2304, 2304, 384, 384,
      24960, 65};
  if (n_in != 20) { const_kernel<<<outg, blk, 0, stream>>>(out, out_size, 5.0f); return; }
  for (int i = 0; i < 20; i++)
    if (in_sizes[i] != expected[i]) {
      const_kernel<<<outg, blk, 0, stream>>>(out, out_size, 10.0f * (i + 1));
      return;
    }
  if (out_size != BT * V_) { const_kernel<<<outg, blk, 0, stream>>>(out, out_size, 7.0f); return; }

  const void* idx   = d_in[0];
  const void* tok   = d_in[1];
  const void* pos   = d_in[2];
  const void* Wq    = d_in[3];
  const void* Wk    = d_in[4];
  const void* Wv    = d_in[5];
  const void* Wproj = d_in[6];
  const void* bproj = d_in[7];
  const void* W1    = d_in[8];
  const void* b1    = d_in[9];
  const void* W2    = d_in[10];
  const void* b2    = d_in[11];
  const void* ln1g  = d_in[12];
  const void* ln1b  = d_in[13];
  const void* ln2g  = d_in[14];
  const void* ln2b  = d_in[15];
  const void* lnfg  = d_in[16];
  const void* lnfb  = d_in[17];
  const void* Whead = d_in[18];
  const void* bhead = d_in[19];

  // Workspace layout:
  //  flags(256) | x bf16[BT*D] | st float2[BT] | Wbuf bf16[WBUF_E] |
  //  Hbuf bf16[HBUF_E pad] | region
  const size_t off_x  = 256;
  const size_t off_st = off_x + (size_t)BT * D_ * 2;
  const size_t off_wb = off_st + (size_t)BT * 8;
  const size_t off_hb = off_wb + (size_t)WBUF_E * 2;
  const size_t fixed  = off_hb + ((size_t)HBUF_E * 2 + 63) / 64 * 64;
  if (ws_size < fixed + (size_t)BT * D_ * 2 / 4) {
    const_kernel<<<outg, blk, 0, stream>>>(out, out_size, 0.0f);
    return;
  }
  size_t region = ws_size - fixed;

  // Attention chunking: prefer FULL att (proj in one dispatch).
  int na = 0, fullAtt = 0;
  const int cands[6] = {4, 8, 16, 32, 64, 0};
  for (int i = 0; cands[i]; i++) {
    size_t need = ((size_t)3 * (BT / cands[i]) + BT) * D_ * 2;
    if (need <= region) { na = cands[i]; fullAtt = 1; break; }
  }
  if (!na) {
    for (int i = 0; cands[i]; i++) {
      size_t need = (size_t)4 * (BT / cands[i]) * D_ * 2;
      if (need <= region) { na = cands[i]; break; }
    }
  }
  if (!na) { const_kernel<<<outg, blk, 0, stream>>>(out, out_size, 0.0f); return; }
  int nf = 0;
  const int candf[7] = {2, 4, 8, 16, 32, 64, 0};
  for (int i = 0; candf[i]; i++) {
    if ((size_t)4 * (BT / candf[i]) * D_ * 2 <= region) { nf = candf[i]; break; }
  }
  const int MCa = BT / na, MCf = BT / nf;

  char* wsb = (char*)d_ws;
  unsigned* flags = (unsigned*)wsb;
  bf16*   x    = (bf16*)(wsb + off_x);
  float2* st   = (float2*)(wsb + off_st);
  bf16*   Wbuf = (bf16*)(wsb + off_wb);
  bf16*   Hbuf = (bf16*)(wsb + off_hb);
  bf16*   qkvc = (bf16*)(wsb + fixed);
  bf16*   att  = qkvc + (size_t)3 * MCa * D_;   // full (FULL) or chunk (else)
  bf16*   midc = qkvc;                           // overlays after attention

  detect_kernel<<<dim3(20), blk, 0, stream>>>(
      tok, pos, Wq, Wk, Wv, Wproj, bproj, W1, b1, W2, b2,
      ln1g, ln1b, ln2g, ln2b, lnfg, lnfb, Whead, bhead,
      (const int*)idx, flags);
  embed_kernel<<<dim3(BT * D_ / 256), blk, 0, stream>>>(idx, tok, pos, x, flags);
  conv_head<<<dim3((HBUF_E + 255) / 256), blk, 0, stream>>>(
      Whead, bhead, lnfg, lnfb, flags, Hbuf);

  for (int l = 0; l < L_; l++) {
    conv_layer<<<dim3((WBUF_E + 255) / 256), blk, 0, stream>>>(
        Wq, Wk, Wv, Wproj, bproj, W1, b1, W2, b2,
        ln1g, ln1b, ln2g, ln2b, flags, Wbuf, l);
    stats_kernel<<<dim3(BT / 4), blk, 0, stream>>>(x, st);
    if (fullAtt) {
      for (int c = 0; c < na; c++) {
        int tok0 = c * MCa;
        qkv_mfma<<<dim3(MCa / 128, 18), blk, 0, stream>>>(x, st, Wbuf, qkvc, MCa, tok0);
        attn_kernel<<<dim3(H_ * MCa / 4), blk, 0, stream>>>(
            qkvc, qkvc + (size_t)MCa * D_, qkvc + (size_t)2 * MCa * D_, att, MCa, tok0);
      }
      proj_mfma<<<dim3(6, BT / 128), blk, 0, stream>>>(att, Wbuf, x, 0);
    } else {
      for (int c = 0; c < na; c++) {
        int tok0 = c * MCa;
        qkv_mfma<<<dim3(MCa / 128, 18), blk, 0, stream>>>(x, st, Wbuf, qkvc, MCa, tok0);
        attn_kernel<<<dim3(H_ * MCa / 4), blk, 0, stream>>>(
            qkvc, qkvc + (size_t)MCa * D_, qkvc + (size_t)2 * MCa * D_, att, MCa, 0);
        proj_mfma<<<dim3(6, MCa / 128), blk, 0, stream>>>(att, Wbuf, x, tok0);
      }
    }
    stats_kernel<<<dim3(BT / 4), blk, 0, stream>>>(x, st);
    for (int f = 0; f < nf; f++) {
      int tok0 = f * MCf;
      ffn1_mfma<<<dim3(24, MCf / 128), blk, 0, stream>>>(x, st, Wbuf, midc, tok0);
      ffn2_mfma<<<dim3(6, MCf / 128), blk, 0, stream>>>(midc, Wbuf, x, tok0);
    }
  }

  stats_kernel<<<dim3(BT / 4), blk, 0, stream>>>(x, st);
  head_mfma<<<dim3(2, BT / 128), blk, 0, stream>>>(x, st, Hbuf, out);
}

// Round 11
// 3162.671 us; speedup vs baseline: 4.2692x; 1.0715x over previous
//
#include <hip/hip_runtime.h>
#include <hip/hip_bf16.h>

// Problem constants
#define B_  64
#define T_  256
#define D_  384
#define H_  6
#define HD_ 64
#define L_  6
#define V_  65
#define BT  (B_*T_)     // 16384 tokens

typedef __hip_bfloat16 bf16;
typedef unsigned short u16;
typedef short s16;
typedef __attribute__((ext_vector_type(8))) short bf16x8;   // 8 bf16 = 4 VGPR
typedef __attribute__((ext_vector_type(4))) float f32x4;

// Per-layer weight buffer element offsets (bf16 elems)
#define OFF_QKV   0            // [mat][h][hd][d], 18 blocks of 24576
#define OFF_PROJ  442368       // [n][k] 384x384
#define OFF_W1T   589824       // [n][k] 1536x384
#define OFF_W2T   1179648      // [n][k] 384x1536
#define OFF_BPROJ 1769472
#define OFF_B1    1769856
#define OFF_B2    1771392
#define OFF_LN1G  1771776
#define OFF_LN1B  1772160
#define OFF_LN2G  1772544
#define OFF_LN2B  1772928
#define WBUF_E    1773312
// Head buffer
#define HOFF_WHT  0            // [n][k] 65x384
#define HOFF_BH   24960
#define HOFF_LNFG 25088
#define HOFF_LNFB 25472
#define HBUF_E    25856

__device__ __forceinline__ float u2f(u16 u) {
  union { unsigned i; float f; } c; c.i = ((unsigned)u) << 16; return c.f;
}
__device__ __forceinline__ bf16 f2b(float x) { return __float2bfloat16(x); }
__device__ __forceinline__ float b2f(bf16 x) { return __bfloat162float(x); }
__device__ __forceinline__ u16 f2u(float x) { bf16 h = f2b(x); return *(u16*)&h; }

__device__ __forceinline__ float pload(const void* p, size_t i, bool f32w) {
  return f32w ? ((const float*)p)[i] : u2f(((const u16*)p)[i]);
}

// ---------------------------------------------------------------------------
// Parallel per-tensor dtype detect (R8-proven). flags[j]=1 => f32 storage.
// flags[20]=1 => idx int64.
// ---------------------------------------------------------------------------
__global__ __launch_bounds__(256) void detect_kernel(
    const void* p1,  const void* p2,  const void* p3,  const void* p4,
    const void* p5,  const void* p6,  const void* p7,  const void* p8,
    const void* p9,  const void* p10, const void* p11, const void* p12,
    const void* p13, const void* p14, const void* p15, const void* p16,
    const void* p17, const void* p18, const void* p19,
    const int* __restrict__ idx, unsigned* flags)
{
  const void* ps[20] = {nullptr, p1, p2, p3, p4, p5, p6, p7, p8, p9, p10,
                        p11, p12, p13, p14, p15, p16, p17, p18, p19};
  const int esz[20] = {16384, 24960, 98304, 884736, 884736, 884736, 884736,
                       2304, 3538944, 9216, 3538944, 2304, 2304, 2304, 2304,
                       2304, 384, 384, 24960, 65};
  __shared__ int r1[256], r2[256];
  int bid = blockIdx.x, tid = threadIdx.x;
  if (bid == 19) {
    int z = 0;
    for (int m = tid; m < 4096; m += 256) z += (idx[2 * m + 1] == 0) ? 1 : 0;
    r1[tid] = z; __syncthreads();
    for (int s = 128; s > 0; s >>= 1) {
      if (tid < s) r1[tid] += r1[tid + s];
      __syncthreads();
    }
    if (tid == 0) flags[20] = (r1[0] >= 4000) ? 1u : 0u;
    return;
  }
  int j = bid + 1;
  const u16* p = (const u16*)ps[j];
  int ns = esz[j] / 2; if (ns > 1024) ns = 1024;
  int band = 0, nz = 0;
  for (int i = tid; i < ns; i += 256) {
    u16 lo = p[2 * i], hi = p[2 * i + 1];
    int e = (lo >> 7) & 0xFF;
    band += (e >= 100 && e <= 127) ? 1 : 0;
    nz   += (lo | hi) ? 1 : 0;
  }
  r1[tid] = band; r2[tid] = nz; __syncthreads();
  for (int s = 128; s > 0; s >>= 1) {
    if (tid < s) { r1[tid] += r1[tid + s]; r2[tid] += r2[tid + s]; }
    __syncthreads();
  }
  if (tid == 0) flags[j] = (r2[0] > 0 && r1[0] * 2 < ns) ? 1u : 0u;
}

__global__ void const_kernel(float* out, int n, float val) {
  int i = blockIdx.x * 256 + threadIdx.x;
  if (i < n) out[i] = val;
}

// ---------------------------------------------------------------------------
// Per-layer weight convert+transpose to bf16.
// ---------------------------------------------------------------------------
__global__ __launch_bounds__(256) void conv_layer(
    const void* Wq, const void* Wk, const void* Wv, const void* Wproj,
    const void* bproj, const void* W1, const void* b1, const void* W2,
    const void* b2, const void* ln1g, const void* ln1b, const void* ln2g,
    const void* ln2b, const unsigned* __restrict__ flags,
    bf16* __restrict__ dst, int l)
{
  int e = blockIdx.x * 256 + threadIdx.x;
  if (e >= WBUF_E) return;
  float v;
  if (e < OFF_PROJ) {                       // QKV^T per head
    int math = e / 24576;
    int rem  = e - math * 24576;
    int hd = rem / 384, d = rem - hd * 384;
    int mat = math / 6, hh = math - mat * 6;
    const void* src = (mat == 0 ? Wq : mat == 1 ? Wk : Wv);
    v = pload(src, ((size_t)(l * 6 + hh) * 384 + d) * 64 + hd, flags[3 + mat] != 0);
  } else if (e < OFF_W1T) {                 // Wproj^T
    int e2 = e - OFF_PROJ;
    int n = e2 / 384, d = e2 - n * 384;
    v = pload(Wproj, ((size_t)l * 384 + d) * 384 + n, flags[6] != 0);
  } else if (e < OFF_W2T) {                 // W1^T
    int e2 = e - OFF_W1T;
    int n = e2 / 384, d = e2 - n * 384;
    v = pload(W1, ((size_t)l * 384 + d) * 1536 + n, flags[8] != 0);
  } else if (e < OFF_BPROJ) {               // W2^T
    int e2 = e - OFF_W2T;
    int n = e2 / 1536, k = e2 - n * 1536;
    v = pload(W2, ((size_t)l * 1536 + k) * 384 + n, flags[10] != 0);
  } else {
    int e2 = e - OFF_BPROJ;
    if      (e2 < 384)  v = pload(bproj, (size_t)l * 384 + e2, flags[7] != 0);
    else if (e2 < 1920) v = pload(b1, (size_t)l * 1536 + (e2 - 384), flags[9] != 0);
    else if (e2 < 2304) v = pload(b2, (size_t)l * 384 + (e2 - 1920), flags[11] != 0);
    else if (e2 < 2688) v = pload(ln1g, (size_t)l * 384 + (e2 - 2304), flags[12] != 0);
    else if (e2 < 3072) v = pload(ln1b, (size_t)l * 384 + (e2 - 2688), flags[13] != 0);
    else if (e2 < 3456) v = pload(ln2g, (size_t)l * 384 + (e2 - 3072), flags[14] != 0);
    else                v = pload(ln2b, (size_t)l * 384 + (e2 - 3456), flags[15] != 0);
  }
  dst[e] = f2b(v);
}

__global__ __launch_bounds__(256) void conv_head(
    const void* Wh, const void* bh, const void* lnfg, const void* lnfb,
    const unsigned* __restrict__ flags, bf16* __restrict__ dst)
{
  int e = blockIdx.x * 256 + threadIdx.x;
  if (e >= HBUF_E) return;
  float v = 0.f;
  if (e < HOFF_BH) {                        // Whead^T [65][384]
    int n = e / 384, d = e - n * 384;
    v = pload(Wh, (size_t)d * 65 + n, flags[18] != 0);
  } else if (e < 25025) {
    v = pload(bh, e - HOFF_BH, flags[19] != 0);
  } else if (e < HOFF_LNFG) {
    v = 0.f;
  } else if (e < HOFF_LNFB) {
    v = pload(lnfg, e - HOFF_LNFG, flags[16] != 0);
  } else {
    v = pload(lnfb, e - HOFF_LNFB, flags[17] != 0);
  }
  dst[e] = f2b(v);
}

// ---------------------------------------------------------------------------
__global__ __launch_bounds__(256) void embed_kernel(
    const void* __restrict__ idx, const void* __restrict__ tok,
    const void* __restrict__ pos, bf16* __restrict__ x,
    const unsigned* __restrict__ flags)
{
  int i   = blockIdx.x * 256 + threadIdx.x;   // < BT*D_
  int tkn = i / D_;
  int d   = i - tkn * D_;
  int t   = tkn & (T_ - 1);
  long long tix;
  if (flags[20]) tix = ((const long long*)idx)[tkn];
  else           tix = ((const int*)idx)[tkn];
  float v = pload(tok, (size_t)tix * D_ + d, flags[1] != 0)
          + pload(pos, (size_t)t * D_ + d, flags[2] != 0);
  x[i] = f2b(v);
}

// ---------------------------------------------------------------------------
// Per-token LN stats: mean, rsqrt(var+eps). One wave per token.
// ---------------------------------------------------------------------------
__global__ __launch_bounds__(256) void stats_kernel(
    const bf16* __restrict__ x, float2* __restrict__ st)
{
  int w = threadIdx.x >> 6, lane = threadIdx.x & 63;
  int tok = blockIdx.x * 4 + w;
  const bf16* xr = x + (size_t)tok * D_;
  float v[6]; float s = 0.f;
#pragma unroll
  for (int j = 0; j < 6; j++) { v[j] = b2f(xr[lane + 64 * j]); s += v[j]; }
#pragma unroll
  for (int o = 1; o < 64; o <<= 1) s += __shfl_xor(s, o, 64);
  float mean = s * (1.0f / D_);
  float sq = 0.f;
#pragma unroll
  for (int j = 0; j < 6; j++) { float d0 = v[j] - mean; sq += d0 * d0; }
#pragma unroll
  for (int o = 1; o < 64; o <<= 1) sq += __shfl_xor(sq, o, 64);
  if (lane == 0) {
    float inv = 1.0f / sqrtf(sq * (1.0f / D_) + 1e-3f);
    st[tok] = make_float2(mean, inv);
  }
}

// ---------------------------------------------------------------------------
// MFMA GEMM core (R10-proven). Tile 128m x 64n x 64k.
// ---------------------------------------------------------------------------
#define XS_S 72
#define WT_S 72

template<int AMODE, int RELU, int RESID, int OUTF32, int BIAS>
__device__ __forceinline__ void mgemm_core(
    s16* __restrict__ Xs, s16* __restrict__ Wt,
    const u16* __restrict__ A, const float2* __restrict__ st,
    const u16* __restrict__ lng, const u16* __restrict__ lnb,
    const u16* __restrict__ WT, const bf16* __restrict__ bias,
    const bf16* __restrict__ resid, void* __restrict__ Cout,
    int ldC, int N, int K, int arow0, int crow0, int n0)
{
  int tid = threadIdx.x;
  int w = tid >> 6, lane = tid & 63;
  int quad = lane >> 4, l15 = lane & 15;
  f32x4 acc[2][4];
#pragma unroll
  for (int i = 0; i < 2; i++)
#pragma unroll
    for (int j = 0; j < 4; j++) acc[i][j] = (f32x4){0.f, 0.f, 0.f, 0.f};

  int xr = tid >> 1, xc = (tid & 1) * 32;
  int wn = tid >> 2, wk = (tid & 3) * 16;
  float mean = 0.f, inv = 1.f;
  if (AMODE) { float2 s2 = st[arow0 + xr]; mean = s2.x; inv = s2.y; }
  const u16* Ap0 = A + (size_t)(arow0 + xr) * K + xc;
  bool wvalid = (n0 + wn) < N;
  const u16* Wp0 = WT + (size_t)(wvalid ? (n0 + wn) : 0) * K + wk;

  for (int k0 = 0; k0 < K; k0 += 64) {
    bf16x8 xv[4];
#pragma unroll
    for (int i = 0; i < 4; i++) xv[i] = *(const bf16x8*)(Ap0 + k0 + 8 * i);
    if (AMODE) {
#pragma unroll
      for (int i = 0; i < 4; i++) {
        bf16x8 g = *(const bf16x8*)(lng + xc + k0 + 8 * i);
        bf16x8 b = *(const bf16x8*)(lnb + xc + k0 + 8 * i);
#pragma unroll
        for (int j = 0; j < 8; j++) {
          float f = (u2f((u16)xv[i][j]) - mean) * inv * u2f((u16)g[j])
                  + u2f((u16)b[j]);
          xv[i][j] = (s16)f2u(f);
        }
      }
    }
    bf16x8 wv[2];
#pragma unroll
    for (int i = 0; i < 2; i++)
      wv[i] = wvalid ? *(const bf16x8*)(Wp0 + k0 + 8 * i)
                     : (bf16x8){0,0,0,0,0,0,0,0};
    __syncthreads();
#pragma unroll
    for (int i = 0; i < 4; i++)
      *(bf16x8*)&Xs[xr * XS_S + xc + 8 * i] = xv[i];
#pragma unroll
    for (int i = 0; i < 2; i++)
      *(bf16x8*)&Wt[wn * WT_S + wk + 8 * i] = wv[i];
    __syncthreads();
#pragma unroll
    for (int kh = 0; kh < 2; kh++) {
      int kk = kh * 32 + quad * 8;
      bf16x8 a0 = *(const bf16x8*)&Xs[(w * 32 + l15) * XS_S + kk];
      bf16x8 a1 = *(const bf16x8*)&Xs[(w * 32 + 16 + l15) * XS_S + kk];
#pragma unroll
      for (int nt = 0; nt < 4; nt++) {
        bf16x8 b = *(const bf16x8*)&Wt[(nt * 16 + l15) * WT_S + kk];
        acc[0][nt] = __builtin_amdgcn_mfma_f32_16x16x32_bf16(a0, b, acc[0][nt], 0, 0, 0);
        acc[1][nt] = __builtin_amdgcn_mfma_f32_16x16x32_bf16(a1, b, acc[1][nt], 0, 0, 0);
      }
    }
  }

#pragma unroll
  for (int sub = 0; sub < 2; sub++)
#pragma unroll
    for (int nt = 0; nt < 4; nt++)
#pragma unroll
      for (int r = 0; r < 4; r++) {
        int m = w * 32 + sub * 16 + quad * 4 + r;
        int n = n0 + nt * 16 + l15;
        if (n < N) {
          float v = acc[sub][nt][r];
          if (BIAS)  v += b2f(bias[n]);
          if (RESID) v += b2f(resid[(size_t)(crow0 + m) * ldC + n]);
          if (RELU)  v = fmaxf(v, 0.f);
          if (OUTF32) ((float*)Cout)[(size_t)(crow0 + m) * ldC + n] = v;
          else        ((bf16*)Cout)[(size_t)(crow0 + m) * ldC + n]  = f2b(v);
        }
      }
}

#define MGEMM_LDS __shared__ s16 Xs[128 * XS_S]; __shared__ s16 Wt[64 * WT_S];

__global__ __launch_bounds__(256) void qkv_mfma(
    const bf16* x, const float2* st, const bf16* Wbuf, bf16* qkvc,
    int MCa, int tok0)
{
  MGEMM_LDS
  int zi = blockIdx.y;
  int mat = zi / H_, hh = zi - mat * H_;
  const u16* W = (const u16*)Wbuf + OFF_QKV + (size_t)zi * HD_ * D_;
  bf16* Cp = qkvc + (size_t)mat * MCa * D_ + (size_t)hh * MCa * HD_;
  int m0 = blockIdx.x * 128;
  mgemm_core<1,0,0,0,0>(Xs, Wt, (const u16*)x, st,
                        (const u16*)Wbuf + OFF_LN1G, (const u16*)Wbuf + OFF_LN1B,
                        W, nullptr, nullptr, Cp, HD_, HD_, D_,
                        tok0 + m0, m0, 0);
}

__global__ __launch_bounds__(256) void proj_mfma(
    const bf16* A, const bf16* Wbuf, bf16* x, int tok0)
{
  MGEMM_LDS
  int n0 = blockIdx.x * 64, m0 = blockIdx.y * 128;
  mgemm_core<0,0,1,0,1>(Xs, Wt, (const u16*)A, nullptr, nullptr, nullptr,
                        (const u16*)Wbuf + OFF_PROJ, (const bf16*)Wbuf + OFF_BPROJ,
                        x, x, D_, D_, D_, m0, tok0 + m0, n0);
}

__global__ __launch_bounds__(256) void ffn1_mfma(
    const bf16* x, const float2* st, const bf16* Wbuf, bf16* midc, int tok0)
{
  MGEMM_LDS
  int n0 = blockIdx.x * 64, m0 = blockIdx.y * 128;
  mgemm_core<1,1,0,0,1>(Xs, Wt, (const u16*)x, st,
                        (const u16*)Wbuf + OFF_LN2G, (const u16*)Wbuf + OFF_LN2B,
                        (const u16*)Wbuf + OFF_W1T, (const bf16*)Wbuf + OFF_B1,
                        nullptr, midc, 4 * D_, 4 * D_, D_,
                        tok0 + m0, m0, n0);
}

__global__ __launch_bounds__(256) void ffn2_mfma(
    const bf16* midc, const bf16* Wbuf, bf16* x, int tok0)
{
  MGEMM_LDS
  int n0 = blockIdx.x * 64, m0 = blockIdx.y * 128;
  mgemm_core<0,0,1,0,1>(Xs, Wt, (const u16*)midc, nullptr, nullptr, nullptr,
                        (const u16*)Wbuf + OFF_W2T, (const bf16*)Wbuf + OFF_B2,
                        x, x, D_, D_, 4 * D_, m0, tok0 + m0, n0);
}

__global__ __launch_bounds__(256) void head_mfma(
    const bf16* x, const float2* st, const bf16* Hbuf, float* out)
{
  MGEMM_LDS
  int n0 = blockIdx.x * 64, m0 = blockIdx.y * 128;
  mgemm_core<1,0,0,1,1>(Xs, Wt, (const u16*)x, st,
                        (const u16*)Hbuf + HOFF_LNFG, (const u16*)Hbuf + HOFF_LNFB,
                        (const u16*)Hbuf + HOFF_WHT, (const bf16*)Hbuf + HOFF_BH,
                        nullptr, out, V_, V_, D_, m0, m0, n0);
}

// ---------------------------------------------------------------------------
// MFMA flash-style causal attention. One block per (b,h,qtile of 64 rows).
// Phase 1: QK^T via mfma (all <=4 K-chunks, scores live in 16 f32x4/lane).
// Softmax per-row via 16-lane shfl groups. Phase 2: P->LDS (A-layout
// round-trip), PV via mfma with V gathered from native [s][d] LDS.
// Fragment maps identical to mgemm_core (HW-verified R9/R10).
// ---------------------------------------------------------------------------
#define VS_S 73
__global__ __launch_bounds__(256) void attn3_kernel(
    const bf16* __restrict__ Q, const bf16* __restrict__ K,
    const bf16* __restrict__ V, bf16* __restrict__ att, int MCa, int row0)
{
  __shared__ s16 Qs[64 * 72];
  __shared__ s16 Ks[64 * 72];
  __shared__ s16 Vs[64 * VS_S];
  __shared__ s16 Ps[4][16 * 72];
  const float scale = 0.05103103630798288f;   // 384^-0.5 (full-D scaling!)
  int tid = threadIdx.x;
  int w = tid >> 6, lane = tid & 63;
  int quad = lane >> 4, l15 = lane & 15;
  int bid = blockIdx.x;
  int qt = bid & 3;
  int bh = bid >> 2;
  int b = bh / H_, h = bh - b * H_;
  size_t base = ((size_t)h * MCa + (size_t)b * T_) * HD_;
  int q0 = qt * 64;
  int cq = qt;                               // chunks 0..cq (diag = cq)

  // stage Q tile (64 rows x 64 d)
#pragma unroll
  for (int i = 0; i < 2; i++) {
    int e = i * 256 + tid;                   // bf16x8 units: 512 total
    int r = e >> 3, c = (e & 7) * 8;
    *(bf16x8*)&Qs[r * 72 + c] =
        *(const bf16x8*)((const u16*)Q + base + (size_t)(q0 + r) * HD_ + c);
  }

  f32x4 S[4][4];
  // ---- Phase 1: scores ----
  for (int c = 0; c <= cq; c++) {
#pragma unroll
    for (int nt = 0; nt < 4; nt++) S[c][nt] = (f32x4){0.f, 0.f, 0.f, 0.f};
    __syncthreads();
#pragma unroll
    for (int i = 0; i < 2; i++) {
      int e = i * 256 + tid;
      int r = e >> 3, cc = (e & 7) * 8;
      *(bf16x8*)&Ks[r * 72 + cc] =
          *(const bf16x8*)((const u16*)K + base + (size_t)(c * 64 + r) * HD_ + cc);
    }
    __syncthreads();
#pragma unroll
    for (int ks = 0; ks < 2; ks++) {
      int kk = ks * 32 + quad * 8;
      bf16x8 a = *(const bf16x8*)&Qs[(w * 16 + l15) * 72 + kk];
#pragma unroll
      for (int nt = 0; nt < 4; nt++) {
        bf16x8 bb = *(const bf16x8*)&Ks[(nt * 16 + l15) * 72 + kk];
        S[c][nt] = __builtin_amdgcn_mfma_f32_16x16x32_bf16(a, bb, S[c][nt], 0, 0, 0);
      }
    }
  }

  // scale + causal mask (only diagonal chunk cq needs masking)
#pragma unroll
  for (int nt = 0; nt < 4; nt++)
#pragma unroll
    for (int r = 0; r < 4; r++) {
      int qrow = q0 + w * 16 + quad * 4 + r;
      for (int c = 0; c <= cq; c++) {
        float v = S[c][nt][r] * scale;
        int sg = c * 64 + nt * 16 + l15;
        S[c][nt][r] = (sg <= qrow) ? v : -1e30f;
      }
    }

  // row softmax stats (rows = quad*4+r; reduce across 16-lane group)
  float mr[4], sr[4];
#pragma unroll
  for (int r = 0; r < 4; r++) {
    float m = -1e30f;
    for (int c = 0; c <= cq; c++)
#pragma unroll
      for (int nt = 0; nt < 4; nt++) m = fmaxf(m, S[c][nt][r]);
#pragma unroll
    for (int o = 1; o < 16; o <<= 1) m = fmaxf(m, __shfl_xor(m, o, 64));
    mr[r] = m;
    float s = 0.f;
    for (int c = 0; c <= cq; c++)
#pragma unroll
      for (int nt = 0; nt < 4; nt++) {
        float p = __expf(S[c][nt][r] - m);
        S[c][nt][r] = p;
        s += p;
      }
#pragma unroll
    for (int o = 1; o < 16; o <<= 1) s += __shfl_xor(s, o, 64);
    sr[r] = 1.0f / s;
  }

  // ---- Phase 2: PV ----
  f32x4 O[4];
#pragma unroll
  for (int nt = 0; nt < 4; nt++) O[nt] = (f32x4){0.f, 0.f, 0.f, 0.f};

  for (int c = 0; c <= cq; c++) {
    __syncthreads();
#pragma unroll
    for (int i = 0; i < 2; i++) {
      int e = i * 256 + tid;                 // ushort4 units over 64x64
      int r = e >> 3, cc = (e & 7) * 8;
      const u16* src = (const u16*)V + base + (size_t)(c * 64 + r) * HD_ + cc;
      bf16x8 vv = *(const bf16x8*)src;
#pragma unroll
      for (int k = 0; k < 8; k++) Vs[r * VS_S + cc + k] = vv[k];
    }
    // write P chunk (C-layout -> LDS rows m, cols s) — own-wave region
#pragma unroll
    for (int nt = 0; nt < 4; nt++)
#pragma unroll
      for (int r = 0; r < 4; r++)
        Ps[w][(quad * 4 + r) * 72 + nt * 16 + l15] = (s16)f2u(S[c][nt][r]);
    __syncthreads();
#pragma unroll
    for (int ks = 0; ks < 2; ks++) {
      bf16x8 a = *(const bf16x8*)&Ps[w][l15 * 72 + ks * 32 + quad * 8];
#pragma unroll
      for (int nt = 0; nt < 4; nt++) {
        bf16x8 bb;
#pragma unroll
        for (int j = 0; j < 8; j++)
          bb[j] = Vs[(ks * 32 + quad * 8 + j) * VS_S + nt * 16 + l15];
        O[nt] = __builtin_amdgcn_mfma_f32_16x16x32_bf16(a, bb, O[nt], 0, 0, 0);
      }
    }
  }

  // normalize + write (C layout: row=quad*4+r, col=nt*16+l15)
#pragma unroll
  for (int nt = 0; nt < 4; nt++)
#pragma unroll
    for (int r = 0; r < 4; r++) {
      int qrow = q0 + w * 16 + quad * 4 + r;
      float o = O[nt][r] * sr[r];
      att[(size_t)(row0 + b * T_ + qrow) * D_ + h * HD_ + nt * 16 + l15] = f2b(o);
    }
}

// ---------------------------------------------------------------------------
extern "C" void kernel_launch(void* const* d_in, const int* in_sizes, int n_in,
                              void* d_out, int out_size, void* d_ws, size_t ws_size,
                              hipStream_t stream)
{
  float* out = (float*)d_out;
  dim3 blk(256);
  int outg = (out_size + 255) / 256;

  static const int expected[20] = {
      16384, 24960, 98304, 884736, 884736, 884736, 884736, 2304,
      3538944, 9216, 3538944, 2304, 2304, 2304, 2304, 2304, 384, 384,
      24960, 65};
  if (n_in != 20) { const_kernel<<<outg, blk, 0, stream>>>(out, out_size, 5.0f); return; }
  for (int i = 0; i < 20; i++)
    if (in_sizes[i] != expected[i]) {
      const_kernel<<<outg, blk, 0, stream>>>(out, out_size, 10.0f * (i + 1));
      return;
    }
  if (out_size != BT * V_) { const_kernel<<<outg, blk, 0, stream>>>(out, out_size, 7.0f); return; }

  const void* idx   = d_in[0];
  const void* tok   = d_in[1];
  const void* pos   = d_in[2];
  const void* Wq    = d_in[3];
  const void* Wk    = d_in[4];
  const void* Wv    = d_in[5];
  const void* Wproj = d_in[6];
  const void* bproj = d_in[7];
  const void* W1    = d_in[8];
  const void* b1    = d_in[9];
  const void* W2    = d_in[10];
  const void* b2    = d_in[11];
  const void* ln1g  = d_in[12];
  const void* ln1b  = d_in[13];
  const void* ln2g  = d_in[14];
  const void* ln2b  = d_in[15];
  const void* lnfg  = d_in[16];
  const void* lnfb  = d_in[17];
  const void* Whead = d_in[18];
  const void* bhead = d_in[19];

  const size_t off_x  = 256;
  const size_t off_st = off_x + (size_t)BT * D_ * 2;
  const size_t off_wb = off_st + (size_t)BT * 8;
  const size_t off_hb = off_wb + (size_t)WBUF_E * 2;
  const size_t fixed  = off_hb + ((size_t)HBUF_E * 2 + 63) / 64 * 64;
  if (ws_size < fixed + (size_t)BT * D_ * 2 / 4) {
    const_kernel<<<outg, blk, 0, stream>>>(out, out_size, 0.0f);
    return;
  }
  size_t region = ws_size - fixed;

  int na = 0, fullAtt = 0;
  const int cands[6] = {4, 8, 16, 32, 64, 0};
  for (int i = 0; cands[i]; i++) {
    size_t need = ((size_t)3 * (BT / cands[i]) + BT) * D_ * 2;
    if (need <= region) { na = cands[i]; fullAtt = 1; break; }
  }
  if (!na) {
    for (int i = 0; cands[i]; i++) {
      size_t need = (size_t)4 * (BT / cands[i]) * D_ * 2;
      if (need <= region) { na = cands[i]; break; }
    }
  }
  if (!na) { const_kernel<<<outg, blk, 0, stream>>>(out, out_size, 0.0f); return; }
  int nf = 0;
  const int candf[7] = {2, 4, 8, 16, 32, 64, 0};
  for (int i = 0; candf[i]; i++) {
    if ((size_t)4 * (BT / candf[i]) * D_ * 2 <= region) { nf = candf[i]; break; }
  }
  const int MCa = BT / na, MCf = BT / nf;
  const int CBa = MCa / T_;                 // sequences per attention chunk

  char* wsb = (char*)d_ws;
  unsigned* flags = (unsigned*)wsb;
  bf16*   x    = (bf16*)(wsb + off_x);
  float2* st   = (float2*)(wsb + off_st);
  bf16*   Wbuf = (bf16*)(wsb + off_wb);
  bf16*   Hbuf = (bf16*)(wsb + off_hb);
  bf16*   qkvc = (bf16*)(wsb + fixed);
  bf16*   att  = qkvc + (size_t)3 * MCa * D_;
  bf16*   midc = qkvc;

  detect_kernel<<<dim3(20), blk, 0, stream>>>(
      tok, pos, Wq, Wk, Wv, Wproj, bproj, W1, b1, W2, b2,
      ln1g, ln1b, ln2g, ln2b, lnfg, lnfb, Whead, bhead,
      (const int*)idx, flags);
  embed_kernel<<<dim3(BT * D_ / 256), blk, 0, stream>>>(idx, tok, pos, x, flags);
  conv_head<<<dim3((HBUF_E + 255) / 256), blk, 0, stream>>>(
      Whead, bhead, lnfg, lnfb, flags, Hbuf);

  for (int l = 0; l < L_; l++) {
    conv_layer<<<dim3((WBUF_E + 255) / 256), blk, 0, stream>>>(
        Wq, Wk, Wv, Wproj, bproj, W1, b1, W2, b2,
        ln1g, ln1b, ln2g, ln2b, flags, Wbuf, l);
    stats_kernel<<<dim3(BT / 4), blk, 0, stream>>>(x, st);
    if (fullAtt) {
      for (int c = 0; c < na; c++) {
        int tok0 = c * MCa;
        qkv_mfma<<<dim3(MCa / 128, 18), blk, 0, stream>>>(x, st, Wbuf, qkvc, MCa, tok0);
        attn3_kernel<<<dim3(CBa * H_ * 4), blk, 0, stream>>>(
            qkvc, qkvc + (size_t)MCa * D_, qkvc + (size_t)2 * MCa * D_, att, MCa, tok0);
      }
      proj_mfma<<<dim3(6, BT / 128), blk, 0, stream>>>(att, Wbuf, x, 0);
    } else {
      for (int c = 0; c < na; c++) {
        int tok0 = c * MCa;
        qkv_mfma<<<dim3(MCa / 128, 18), blk, 0, stream>>>(x, st, Wbuf, qkvc, MCa, tok0);
        attn3_kernel<<<dim3(CBa * H_ * 4), blk, 0, stream>>>(
            qkvc, qkvc + (size_t)MCa * D_, qkvc + (size_t)2 * MCa * D_, att, MCa, 0);
        proj_mfma<<<dim3(6, MCa / 128), blk, 0, stream>>>(att, Wbuf, x, tok0);
      }
    }
    stats_kernel<<<dim3(BT / 4), blk, 0, stream>>>(x, st);
    for (int f = 0; f < nf; f++) {
      int tok0 = f * MCf;
      ffn1_mfma<<<dim3(24, MCf / 128), blk, 0, stream>>>(x, st, Wbuf, midc, tok0);
      ffn2_mfma<<<dim3(6, MCf / 128), blk, 0, stream>>>(midc, Wbuf, x, tok0);
    }
  }

  stats_kernel<<<dim3(BT / 4), blk, 0, stream>>>(x, st);
  head_mfma<<<dim3(2, BT / 128), blk, 0, stream>>>(x, st, Hbuf, out);
}